// Round 12
// baseline (352.247 us; speedup 1.0000x reference)
//
#include <hip/hip_runtime.h>
#include <hip/hip_bf16.h>

#define NT 64
#define DM 192
#define NITER 8

typedef __attribute__((ext_vector_type(4))) float f32x4;
typedef __attribute__((ext_vector_type(4))) float float4v;
using half2v = __attribute__((ext_vector_type(2))) _Float16;
using half4v = __attribute__((ext_vector_type(4))) _Float16;
using half8v = __attribute__((ext_vector_type(8))) _Float16;

// ws layout (bytes)
#define BIAS_OFF  147456      // 8*6*3*1024 W-frags
#define TAB_OFF   6438912     // BIAS_OFF + 384*16*64*16
#define SCALE_OFF 6444312

__device__ __forceinline__ half4v pk4(float a, float b, float c, float d){
  half2v lo = __builtin_bit_cast(half2v, __builtin_amdgcn_cvt_pkrtz(a, b));
  half2v hi = __builtin_bit_cast(half2v, __builtin_amdgcn_cvt_pkrtz(c, d));
  half4v r; r[0]=lo[0]; r[1]=lo[1]; r[2]=hi[0]; r[3]=hi[1];
  return r;
}

// ---------------- precompute A: W frags in 16x16x32 layout + rpb-mlp table + scales ----------------
// frag(mat, ct, ks): lane holds W'[16ct + (lane&15)][32ks + 8*(lane>>4) + j], j=0..7 (f16).
// Residual fold: q/k/v weights (mats 0..5) get +I.
__global__ __launch_bounds__(384) void pre_a(
  const float* __restrict__ q1w, const float* __restrict__ q2w,
  const float* __restrict__ k1w, const float* __restrict__ k2w,
  const float* __restrict__ v1w, const float* __restrict__ v2w,
  const float* __restrict__ p1w, const float* __restrict__ p2w,
  const float* __restrict__ w1, const float* __restrict__ b1,
  const float* __restrict__ w2, const float* __restrict__ rpbt,
  const float* __restrict__ ls, char* __restrict__ ws)
{
  int blk = blockIdx.x, t = threadIdx.x;
  if (blk < 48) {
    const float* Ws[8] = {q1w,q2w,k1w,k2w,v1w,v2w,p1w,p2w};
    int mat = blk / 6, ct = blk % 6;
    int lane = t & 63, ks = t >> 6;        // ks 0..5, only 0..2 used
    if (ks < 3) {
      const float* W = Ws[mat];
      int c  = 16*ct + (lane & 15);
      int d0 = 32*ks + 8*(lane >> 4);
      half8v h;
      #pragma unroll
      for (int j = 0; j < 8; ++j) {
        float wel = W[c*96 + d0 + j];
        if (mat < 6 && c == d0 + j) wel += 1.0f;   // fold residual identity
        h[j] = (_Float16)wel;
      }
      *(half8v*)(ws + (size_t)((mat*6+ct)*3+ks)*1024 + lane*16) = h;
    }
  } else {
    float* tab = (float*)(ws + TAB_OFF);
    if (t < 225) {
      float t0 = rpbt[2*t], t1 = rpbt[2*t+1];
      float acc[6] = {0,0,0,0,0,0};
      for (int j = 0; j < 128; ++j) {
        float hv = fmaxf(t0*w1[2*j] + t1*w1[2*j+1] + b1[j], 0.f);
        #pragma unroll
        for (int hh = 0; hh < 6; ++hh) acc[hh] += hv * w2[hh*128 + j];
      }
      #pragma unroll
      for (int hh = 0; hh < 6; ++hh) tab[t*6 + hh] = acc[hh];
    }
    if (t >= 240 && t < 246) {
      float* sc = (float*)(ws + SCALE_OFF);
      int i = t - 240;
      sc[i] = expf(fminf(ls[i], 4.605170185988091f)); // log(100)
    }
  }
}

// ---------------- precompute B: bias = 16*sigmoid(rpb)+mask in S^T fragment order ----------------
__global__ __launch_bounds__(256) void pre_b(
  const float* __restrict__ mask, const int* __restrict__ rpi,
  char* __restrict__ ws)
{
  int w = blockIdx.x / 6, h = blockIdx.x % 6;
  int lane = threadIdx.x & 63, nt = threadIdx.x >> 6;
  const float* tab = (const float*)(ws + TAB_OFF);
  float* bias = (float*)(ws + BIAS_OFF);
  #pragma unroll
  for (int mt = 0; mt < 4; ++mt)
    #pragma unroll
    for (int r = 0; r < 4; ++r) {
      int m = 16*mt + ((lane >> 4) << 2) + r;
      int n = 16*nt + (lane & 15);
      int idx = rpi[n*64 + m];
      float tv = tab[idx*6 + h];
      float sg = 16.f / (1.f + expf(-tv));
      float mv = mask[(w*64 + n)*64 + m];
      bias[(size_t)(((w*6+h)*4+mt)*4+nt)*256 + lane*4 + r] = sg + mv;
    }
}

// ---------------- main fused kernel: persistent block = 8 iterations x 2 windows ----------------
// 12 waves = 2 windows x 6 heads. Double-buffered LDS x/o per window slot; next-iteration x
// prefetched (global->reg after softmax, reg->LDS between barriers 2 and 3) so HBM latency
// hides under compute and only the first iteration pays a cold start.
__global__ __launch_bounds__(768, 2) void win_attn(
  const float* __restrict__ x, const char* __restrict__ ws,
  const float* __restrict__ q1b, const float* __restrict__ q2b,
  const float* __restrict__ k1b, const float* __restrict__ k2b,
  const float* __restrict__ v1b, const float* __restrict__ v2b,
  const float* __restrict__ p1b, const float* __restrict__ p2b,
  float* __restrict__ out)
{
  extern __shared__ char smem[];
  _Float16* smh = (_Float16*)smem;                 // [2 wgrp][2 buf][64*200]
  const int tid = threadIdx.x;
  const int wv = tid >> 6, lane = tid & 63;
  const int llo = lane & 15, lhi = lane >> 4;
  const int wgrp = (wv >= 6) ? 1 : 0;
  const int h = wv - 6*wgrp;            // head 0..5
  const int lt = tid - 384*wgrp;        // thread id within window group (0..383)
  const int bbase = blockIdx.x * (2*NITER);
  const int half = (h < 3) ? 0 : 1;
  const int hd0 = 32 * (h % 3);
  const f32x4 zf = {0.f,0.f,0.f,0.f};
  const float scale_h = ((const float*)(ws + SCALE_OFF))[h];
  const float4v* biasf = (const float4v*)(ws + BIAS_OFF);

  // stage row/col for this thread's 8 float4 chunks
  // (chunk it: f4 = lt + it*384 -> row = f4/48, c4 = f4%48)

  // ---- prologue: stage iteration 0 ----
  {
    const float* xg = x + (size_t)(bbase + wgrp) * (NT*DM);
    _Float16* xo = smh + (wgrp*2 + 0)*12800;
    float4v xv[8];
    #pragma unroll
    for (int it = 0; it < 8; ++it) xv[it] = *(const float4v*)(xg + 4*(lt + it*384));
    #pragma unroll
    for (int it = 0; it < 8; ++it) {
      int f4 = lt + it*384;
      int row = f4 / 48, c4 = f4 % 48;
      *(half4v*)(xo + row*200 + c4*4) = pk4(xv[it][0], xv[it][1], xv[it][2], xv[it][3]);
    }
  }
  __syncthreads();

  for (int i = 0; i < NITER; ++i) {
    const int b = bbase + 2*i + wgrp;
    const int w_in = b & 63;
    _Float16* xo = smh + (wgrp*2 + (i&1))*12800;
    _Float16* xn = smh + (wgrp*2 + ((i&1)^1))*12800;

    // ---- joint QK pass (x32): q^T,k^T = W' * x^T (+bias), l2norm -> qf/kf frags ----
    half4v qf[2][4], kf[2][4];
    {
      f32x4 qacc[2][4], kacc[2][4];
      #pragma unroll
      for (int dt = 0; dt < 2; ++dt)
        #pragma unroll
        for (int tt = 0; tt < 4; ++tt) { qacc[dt][tt] = zf; kacc[dt][tt] = zf; }
      __builtin_amdgcn_s_setprio(1);
      #pragma unroll
      for (int ks = 0; ks < 3; ++ks) {
        half8v xf[4];
        #pragma unroll
        for (int tt = 0; tt < 4; ++tt)
          xf[tt] = *(const half8v*)(xo + (16*tt+llo)*200 + half*96 + 32*ks + 8*lhi);
        #pragma unroll
        for (int dt = 0; dt < 2; ++dt) {
          half8v wq = *(const half8v*)(ws + (size_t)(((0+half)*6 + 2*(h%3)+dt)*3 + ks)*1024 + lane*16);
          half8v wk = *(const half8v*)(ws + (size_t)(((2+half)*6 + 2*(h%3)+dt)*3 + ks)*1024 + lane*16);
          #pragma unroll
          for (int tt = 0; tt < 4; ++tt) {
            qacc[dt][tt] = __builtin_amdgcn_mfma_f32_16x16x32_f16(wq, xf[tt], qacc[dt][tt], 0,0,0);
            kacc[dt][tt] = __builtin_amdgcn_mfma_f32_16x16x32_f16(wk, xf[tt], kacc[dt][tt], 0,0,0);
          }
        }
      }
      __builtin_amdgcn_s_setprio(0);
      const float* qbp = half ? q2b : q1b;
      const float* kbp = half ? k2b : k1b;
      float4v qb[2], kb[2];
      #pragma unroll
      for (int dt = 0; dt < 2; ++dt) {
        qb[dt] = *(const float4v*)(qbp + hd0 + 16*dt + 4*lhi);
        kb[dt] = *(const float4v*)(kbp + hd0 + 16*dt + 4*lhi);
      }
      #pragma unroll
      for (int tt = 0; tt < 4; ++tt) {
        float qv[2][4], kv[2][4];
        float sq = 0.f, sk = 0.f;
        #pragma unroll
        for (int dt = 0; dt < 2; ++dt)
          #pragma unroll
          for (int r = 0; r < 4; ++r) {
            qv[dt][r] = qacc[dt][tt][r] + qb[dt][r]; sq += qv[dt][r]*qv[dt][r];
            kv[dt][r] = kacc[dt][tt][r] + kb[dt][r]; sk += kv[dt][r]*kv[dt][r];
          }
        sq += __shfl_xor(sq, 16); sq += __shfl_xor(sq, 32);
        sk += __shfl_xor(sk, 16); sk += __shfl_xor(sk, 32);
        float invq = scale_h / fmaxf(sqrtf(sq), 1e-12f);
        float invk = 1.f / fmaxf(sqrtf(sk), 1e-12f);
        #pragma unroll
        for (int dt = 0; dt < 2; ++dt) {
          qf[dt][tt] = pk4(qv[dt][0]*invq, qv[dt][1]*invq, qv[dt][2]*invq, qv[dt][3]*invq);
          kf[dt][tt] = pk4(kv[dt][0]*invk, kv[dt][1]*invk, kv[dt][2]*invk, kv[dt][3]*invk);
        }
      }
    }

    // ---- S^T (x16, +fused bias), softmax over m -> P^T frags (unnormalized) ----
    half4v pf[4][4];
    float inv_s[4];
    #pragma unroll
    for (int nt = 0; nt < 4; ++nt) {
      f32x4 s[4];
      #pragma unroll
      for (int mt = 0; mt < 4; ++mt) {
        f32x4 t0 = __builtin_amdgcn_mfma_f32_16x16x16f16(kf[0][mt], qf[0][nt], zf, 0,0,0);
        s[mt]    = __builtin_amdgcn_mfma_f32_16x16x16f16(kf[1][mt], qf[1][nt], t0, 0,0,0);
        float4v bb = biasf[(size_t)(((w_in*6 + h)*4 + mt)*4 + nt)*64 + lane];
        s[mt][0] += bb[0]; s[mt][1] += bb[1]; s[mt][2] += bb[2]; s[mt][3] += bb[3];
      }
      float mx = s[0][0];
      #pragma unroll
      for (int mt = 0; mt < 4; ++mt)
        #pragma unroll
        for (int r = 0; r < 4; ++r) mx = fmaxf(mx, s[mt][r]);
      mx = fmaxf(mx, __shfl_xor(mx, 16)); mx = fmaxf(mx, __shfl_xor(mx, 32));
      float e[4][4]; float sum = 0.f;
      #pragma unroll
      for (int mt = 0; mt < 4; ++mt)
        #pragma unroll
        for (int r = 0; r < 4; ++r) { e[mt][r] = __expf(s[mt][r] - mx); sum += e[mt][r]; }
      sum += __shfl_xor(sum, 16); sum += __shfl_xor(sum, 32);
      inv_s[nt] = 1.f / sum;
      #pragma unroll
      for (int mt = 0; mt < 4; ++mt)
        pf[mt][nt] = pk4(e[mt][0], e[mt][1], e[mt][2], e[mt][3]);
    }

    // ---- prefetch next window's x into registers (latency hides under V+PV) ----
    float4v xvn[8];
    if (i < NITER-1) {
      const float* xgn = x + (size_t)(b + 2) * (NT*DM);
      #pragma unroll
      for (int it = 0; it < 8; ++it) xvn[it] = *(const float4v*)(xgn + 4*(lt + it*384));
    }

    // ---- V pass (x32): v = x * Wv'^T (+bias) -> vf frags ----
    half4v vf[4][2];
    {
      f32x4 acc[4][2];
      #pragma unroll
      for (int tt = 0; tt < 4; ++tt) { acc[tt][0] = zf; acc[tt][1] = zf; }
      #pragma unroll
      for (int ks = 0; ks < 3; ++ks) {
        half8v xf[4];
        #pragma unroll
        for (int tt = 0; tt < 4; ++tt)
          xf[tt] = *(const half8v*)(xo + (16*tt+llo)*200 + half*96 + 32*ks + 8*lhi);
        #pragma unroll
        for (int ct = 0; ct < 2; ++ct) {
          half8v wvf = *(const half8v*)(ws + (size_t)(((4+half)*6 + 2*(h%3)+ct)*3 + ks)*1024 + lane*16);
          #pragma unroll
          for (int tt = 0; tt < 4; ++tt)
            acc[tt][ct] = __builtin_amdgcn_mfma_f32_16x16x32_f16(xf[tt], wvf, acc[tt][ct], 0,0,0);
        }
      }
      const float* vbp = half ? v2b : v1b;
      #pragma unroll
      for (int ct = 0; ct < 2; ++ct) {
        float vb = vbp[hd0 + 16*ct + llo];
        #pragma unroll
        for (int tt = 0; tt < 4; ++tt)
          vf[tt][ct] = pk4(acc[tt][ct][0] + vb, acc[tt][ct][1] + vb,
                           acc[tt][ct][2] + vb, acc[tt][ct][3] + vb);
      }
    }

    // ---- o^T = V^T * P^T (x16, all-register), normalize at store ----
    f32x4 oacc[2][4];
    #pragma unroll
    for (int dt = 0; dt < 2; ++dt)
      #pragma unroll
      for (int nt = 0; nt < 4; ++nt) oacc[dt][nt] = zf;
    __builtin_amdgcn_s_setprio(1);
    #pragma unroll
    for (int mt = 0; mt < 4; ++mt)
      #pragma unroll
      for (int dt = 0; dt < 2; ++dt)
        #pragma unroll
        for (int nt = 0; nt < 4; ++nt)
          oacc[dt][nt] = __builtin_amdgcn_mfma_f32_16x16x16f16(vf[mt][dt], pf[mt][nt], oacc[dt][nt], 0,0,0);
    __builtin_amdgcn_s_setprio(0);

    __syncthreads();   // (2) all waves done reading x(cur); prior proj(nxt readers) retired
    // o overlay into cur
    #pragma unroll
    for (int dt = 0; dt < 2; ++dt)
      #pragma unroll
      for (int nt = 0; nt < 4; ++nt)
        *(half4v*)(xo + (16*nt+llo)*200 + 32*h + 16*dt + 4*lhi) =
          pk4(oacc[dt][nt][0]*inv_s[nt], oacc[dt][nt][1]*inv_s[nt],
              oacc[dt][nt][2]*inv_s[nt], oacc[dt][nt][3]*inv_s[nt]);
    // stage next window's x into nxt
    if (i < NITER-1) {
      #pragma unroll
      for (int it = 0; it < 8; ++it) {
        int f4 = lt + it*384;
        int row = f4 / 48, c4 = f4 % 48;
        *(half4v*)(xn + row*200 + c4*4) = pk4(xvn[it][0], xvn[it][1], xvn[it][2], xvn[it][3]);
      }
    }
    __syncthreads();   // (3) o + next-x staged

    // ---- final^T = Wp * o^T (x32) ; wave -> (half, c-tile pair) ----
    const int ph = h & 1;
    const int cp = h >> 1;          // 0..2
    f32x4 facc[2][4];
    #pragma unroll
    for (int cc = 0; cc < 2; ++cc)
      #pragma unroll
      for (int nt = 0; nt < 4; ++nt) facc[cc][nt] = zf;
    #pragma unroll
    for (int ks = 0; ks < 3; ++ks) {
      half8v of[4];
      #pragma unroll
      for (int nt = 0; nt < 4; ++nt)
        of[nt] = *(const half8v*)(xo + (16*nt+llo)*200 + 96*ph + 32*ks + 8*lhi);
      #pragma unroll
      for (int cc = 0; cc < 2; ++cc) {
        half8v wp = *(const half8v*)(ws + (size_t)(((6+ph)*6 + 2*cp+cc)*3 + ks)*1024 + lane*16);
        #pragma unroll
        for (int nt = 0; nt < 4; ++nt)
          facc[cc][nt] = __builtin_amdgcn_mfma_f32_16x16x32_f16(wp, of[nt], facc[cc][nt], 0,0,0);
      }
    }
    const float* pbp = ph ? p2b : p1b;
    float* og = out + (size_t)b * (NT*DM);
    #pragma unroll
    for (int cc = 0; cc < 2; ++cc) {
      float4v pb = *(const float4v*)(pbp + 16*(2*cp+cc) + 4*lhi);
      #pragma unroll
      for (int nt = 0; nt < 4; ++nt) {
        float4v res;
        #pragma unroll
        for (int r = 0; r < 4; ++r) res[r] = facc[cc][nt][r] + pb[r];
        *(float4v*)(og + (size_t)(16*nt+llo)*192 + 96*ph + 16*(2*cp+cc) + 4*lhi) = res;
      }
    }
  }
}

extern "C" void kernel_launch(void* const* d_in, const int* in_sizes, int n_in,
                              void* d_out, int out_size, void* d_ws, size_t ws_size,
                              hipStream_t stream)
{
  const float* x    = (const float*)d_in[0];
  const float* mask = (const float*)d_in[1];
  const float* ls   = (const float*)d_in[2];
  const float* w1   = (const float*)d_in[3];
  const float* b1   = (const float*)d_in[4];
  const float* w2   = (const float*)d_in[5];
  const float* q1w  = (const float*)d_in[6];  const float* q1b = (const float*)d_in[7];
  const float* q2w  = (const float*)d_in[8];  const float* q2b = (const float*)d_in[9];
  const float* k1w  = (const float*)d_in[10]; const float* k1b = (const float*)d_in[11];
  const float* k2w  = (const float*)d_in[12]; const float* k2b = (const float*)d_in[13];
  const float* v1w  = (const float*)d_in[14]; const float* v1b = (const float*)d_in[15];
  const float* v2w  = (const float*)d_in[16]; const float* v2b = (const float*)d_in[17];
  const float* p1w  = (const float*)d_in[18]; const float* p1b = (const float*)d_in[19];
  const float* p2w  = (const float*)d_in[20]; const float* p2b = (const float*)d_in[21];
  const float* rpbt = (const float*)d_in[22];
  const int*   rpi  = (const int*)d_in[23];
  char* ws = (char*)d_ws;
  float* o = (float*)d_out;

  pre_a<<<49, 384, 0, stream>>>(q1w,q2w,k1w,k2w,v1w,v2w,p1w,p2w, w1,b1,w2, rpbt, ls, ws);
  pre_b<<<384, 256, 0, stream>>>(mask, rpi, ws);

  hipFuncSetAttribute((const void*)win_attn,
                      hipFuncAttributeMaxDynamicSharedMemorySize, 102400);
  win_attn<<<256, 768, 102400, stream>>>(x, ws, q1b,q2b,k1b,k2b,v1b,v2b,p1b,p2b, o);
}

// Round 13
// 334.644 us; speedup vs baseline: 1.0526x; 1.0526x over previous
//
#include <hip/hip_runtime.h>
#include <hip/hip_bf16.h>

#define NT 64
#define DM 192
#define NITER 8

typedef __attribute__((ext_vector_type(4))) float f32x4;
typedef __attribute__((ext_vector_type(4))) float float4v;
using half2v = __attribute__((ext_vector_type(2))) _Float16;
using half4v = __attribute__((ext_vector_type(4))) _Float16;
using half8v = __attribute__((ext_vector_type(8))) _Float16;

// ws layout (bytes)
#define BIAS_OFF  147456      // 8*6*3*1024 W-frags
#define TAB_OFF   6438912     // BIAS_OFF + 384*16*64*16
#define SCALE_OFF 6444312

__device__ __forceinline__ half4v pk4(float a, float b, float c, float d){
  half2v lo = __builtin_bit_cast(half2v, __builtin_amdgcn_cvt_pkrtz(a, b));
  half2v hi = __builtin_bit_cast(half2v, __builtin_amdgcn_cvt_pkrtz(c, d));
  half4v r; r[0]=lo[0]; r[1]=lo[1]; r[2]=hi[0]; r[3]=hi[1];
  return r;
}

// ---------------- precompute A: W frags in 16x16x32 layout + rpb-mlp table + scales ----------------
// frag(mat, ct, ks): lane holds W'[16ct + (lane&15)][32ks + 8*(lane>>4) + j], j=0..7 (f16).
// Residual fold: q/k/v weights (mats 0..5) get +I.
__global__ __launch_bounds__(384) void pre_a(
  const float* __restrict__ q1w, const float* __restrict__ q2w,
  const float* __restrict__ k1w, const float* __restrict__ k2w,
  const float* __restrict__ v1w, const float* __restrict__ v2w,
  const float* __restrict__ p1w, const float* __restrict__ p2w,
  const float* __restrict__ w1, const float* __restrict__ b1,
  const float* __restrict__ w2, const float* __restrict__ rpbt,
  const float* __restrict__ ls, char* __restrict__ ws)
{
  int blk = blockIdx.x, t = threadIdx.x;
  if (blk < 48) {
    const float* Ws[8] = {q1w,q2w,k1w,k2w,v1w,v2w,p1w,p2w};
    int mat = blk / 6, ct = blk % 6;
    int lane = t & 63, ks = t >> 6;        // ks 0..5, only 0..2 used
    if (ks < 3) {
      const float* W = Ws[mat];
      int c  = 16*ct + (lane & 15);
      int d0 = 32*ks + 8*(lane >> 4);
      half8v h;
      #pragma unroll
      for (int j = 0; j < 8; ++j) {
        float wel = W[c*96 + d0 + j];
        if (mat < 6 && c == d0 + j) wel += 1.0f;   // fold residual identity
        h[j] = (_Float16)wel;
      }
      *(half8v*)(ws + (size_t)((mat*6+ct)*3+ks)*1024 + lane*16) = h;
    }
  } else {
    float* tab = (float*)(ws + TAB_OFF);
    if (t < 225) {
      float t0 = rpbt[2*t], t1 = rpbt[2*t+1];
      float acc[6] = {0,0,0,0,0,0};
      for (int j = 0; j < 128; ++j) {
        float hv = fmaxf(t0*w1[2*j] + t1*w1[2*j+1] + b1[j], 0.f);
        #pragma unroll
        for (int hh = 0; hh < 6; ++hh) acc[hh] += hv * w2[hh*128 + j];
      }
      #pragma unroll
      for (int hh = 0; hh < 6; ++hh) tab[t*6 + hh] = acc[hh];
    }
    if (t >= 240 && t < 246) {
      float* sc = (float*)(ws + SCALE_OFF);
      int i = t - 240;
      sc[i] = expf(fminf(ls[i], 4.605170185988091f)); // log(100)
    }
  }
}

// ---------------- precompute B: bias = 16*sigmoid(rpb)+mask in S^T fragment order ----------------
__global__ __launch_bounds__(256) void pre_b(
  const float* __restrict__ mask, const int* __restrict__ rpi,
  char* __restrict__ ws)
{
  int w = blockIdx.x / 6, h = blockIdx.x % 6;
  int lane = threadIdx.x & 63, nt = threadIdx.x >> 6;
  const float* tab = (const float*)(ws + TAB_OFF);
  float* bias = (float*)(ws + BIAS_OFF);
  #pragma unroll
  for (int mt = 0; mt < 4; ++mt)
    #pragma unroll
    for (int r = 0; r < 4; ++r) {
      int m = 16*mt + ((lane >> 4) << 2) + r;
      int n = 16*nt + (lane & 15);
      int idx = rpi[n*64 + m];
      float tv = tab[idx*6 + h];
      float sg = 16.f / (1.f + expf(-tv));
      float mv = mask[(w*64 + n)*64 + m];
      bias[(size_t)(((w*6+h)*4+mt)*4+nt)*256 + lane*4 + r] = sg + mv;
    }
}

// ---------------- main fused kernel: persistent, 8 iter x 2 windows, 12 waves ----------------
// r11 dataflow. o goes to a SEPARATE LDS buffer (no pre-barrier needed); next-iteration x
// loads are issued after the post-o barrier so their 32 VGPRs are live only through proj
// (peak ~112 regs, no spill — r12's mistake was holding them across the V/PV peak).
// 2 barriers per iteration; one cold x-load per CU total.
__global__ __launch_bounds__(768, 2) void win_attn(
  const float* __restrict__ x, const char* __restrict__ ws,
  const float* __restrict__ q1b, const float* __restrict__ q2b,
  const float* __restrict__ k1b, const float* __restrict__ k2b,
  const float* __restrict__ v1b, const float* __restrict__ v2b,
  const float* __restrict__ p1b, const float* __restrict__ p2b,
  float* __restrict__ out)
{
  extern __shared__ char smem[];
  _Float16* smh = (_Float16*)smem;       // [2 wgrp][12800] xo, then [2 wgrp][12800] obuf
  const int tid = threadIdx.x;
  const int wv = tid >> 6, lane = tid & 63;
  const int llo = lane & 15, lhi = lane >> 4;
  const int wgrp = (wv >= 6) ? 1 : 0;
  const int h = wv - 6*wgrp;            // head 0..5
  const int lt = tid - 384*wgrp;        // thread id within window group (0..383)
  _Float16* xo = smh + wgrp*12800;
  _Float16* ob = smh + 25600 + wgrp*12800;
  const int bbase = blockIdx.x * (2*NITER);
  const int half = (h < 3) ? 0 : 1;
  const int hd0 = 32 * (h % 3);
  const f32x4 zf = {0.f,0.f,0.f,0.f};
  const float scale_h = ((const float*)(ws + SCALE_OFF))[h];
  const float4v* biasf = (const float4v*)(ws + BIAS_OFF);

  // ---- prologue: stage iteration 0 ----
  {
    const float* xg = x + (size_t)(bbase + wgrp) * (NT*DM);
    float4v xv[8];
    #pragma unroll
    for (int it = 0; it < 8; ++it) xv[it] = *(const float4v*)(xg + 4*(lt + it*384));
    #pragma unroll
    for (int it = 0; it < 8; ++it) {
      int f4 = lt + it*384;
      int row = f4 / 48, c4 = f4 % 48;
      *(half4v*)(xo + row*200 + c4*4) = pk4(xv[it][0], xv[it][1], xv[it][2], xv[it][3]);
    }
  }
  __syncthreads();   // [A0] x staged

  for (int i = 0; i < NITER; ++i) {
    const int b = bbase + 2*i + wgrp;
    const int w_in = b & 63;

    // ---- joint QK pass (x32): q^T,k^T = W' * x^T (+bias), l2norm -> qf/kf frags ----
    half4v qf[2][4], kf[2][4];
    {
      f32x4 qacc[2][4], kacc[2][4];
      #pragma unroll
      for (int dt = 0; dt < 2; ++dt)
        #pragma unroll
        for (int tt = 0; tt < 4; ++tt) { qacc[dt][tt] = zf; kacc[dt][tt] = zf; }
      __builtin_amdgcn_s_setprio(1);
      #pragma unroll
      for (int ks = 0; ks < 3; ++ks) {
        half8v xf[4];
        #pragma unroll
        for (int tt = 0; tt < 4; ++tt)
          xf[tt] = *(const half8v*)(xo + (16*tt+llo)*200 + half*96 + 32*ks + 8*lhi);
        #pragma unroll
        for (int dt = 0; dt < 2; ++dt) {
          half8v wq = *(const half8v*)(ws + (size_t)(((0+half)*6 + 2*(h%3)+dt)*3 + ks)*1024 + lane*16);
          half8v wk = *(const half8v*)(ws + (size_t)(((2+half)*6 + 2*(h%3)+dt)*3 + ks)*1024 + lane*16);
          #pragma unroll
          for (int tt = 0; tt < 4; ++tt) {
            qacc[dt][tt] = __builtin_amdgcn_mfma_f32_16x16x32_f16(wq, xf[tt], qacc[dt][tt], 0,0,0);
            kacc[dt][tt] = __builtin_amdgcn_mfma_f32_16x16x32_f16(wk, xf[tt], kacc[dt][tt], 0,0,0);
          }
        }
      }
      __builtin_amdgcn_s_setprio(0);
      const float* qbp = half ? q2b : q1b;
      const float* kbp = half ? k2b : k1b;
      float4v qb[2], kb[2];
      #pragma unroll
      for (int dt = 0; dt < 2; ++dt) {
        qb[dt] = *(const float4v*)(qbp + hd0 + 16*dt + 4*lhi);
        kb[dt] = *(const float4v*)(kbp + hd0 + 16*dt + 4*lhi);
      }
      #pragma unroll
      for (int tt = 0; tt < 4; ++tt) {
        float qv[2][4], kv[2][4];
        float sq = 0.f, sk = 0.f;
        #pragma unroll
        for (int dt = 0; dt < 2; ++dt)
          #pragma unroll
          for (int r = 0; r < 4; ++r) {
            qv[dt][r] = qacc[dt][tt][r] + qb[dt][r]; sq += qv[dt][r]*qv[dt][r];
            kv[dt][r] = kacc[dt][tt][r] + kb[dt][r]; sk += kv[dt][r]*kv[dt][r];
          }
        sq += __shfl_xor(sq, 16); sq += __shfl_xor(sq, 32);
        sk += __shfl_xor(sk, 16); sk += __shfl_xor(sk, 32);
        float invq = scale_h / fmaxf(sqrtf(sq), 1e-12f);
        float invk = 1.f / fmaxf(sqrtf(sk), 1e-12f);
        #pragma unroll
        for (int dt = 0; dt < 2; ++dt) {
          qf[dt][tt] = pk4(qv[dt][0]*invq, qv[dt][1]*invq, qv[dt][2]*invq, qv[dt][3]*invq);
          kf[dt][tt] = pk4(kv[dt][0]*invk, kv[dt][1]*invk, kv[dt][2]*invk, kv[dt][3]*invk);
        }
      }
    }

    // ---- S^T (x16, +fused bias), softmax over m -> P^T frags (unnormalized) ----
    half4v pf[4][4];
    float inv_s[4];
    #pragma unroll
    for (int nt = 0; nt < 4; ++nt) {
      f32x4 s[4];
      #pragma unroll
      for (int mt = 0; mt < 4; ++mt) {
        f32x4 t0 = __builtin_amdgcn_mfma_f32_16x16x16f16(kf[0][mt], qf[0][nt], zf, 0,0,0);
        s[mt]    = __builtin_amdgcn_mfma_f32_16x16x16f16(kf[1][mt], qf[1][nt], t0, 0,0,0);
        float4v bb = biasf[(size_t)(((w_in*6 + h)*4 + mt)*4 + nt)*64 + lane];
        s[mt][0] += bb[0]; s[mt][1] += bb[1]; s[mt][2] += bb[2]; s[mt][3] += bb[3];
      }
      float mx = s[0][0];
      #pragma unroll
      for (int mt = 0; mt < 4; ++mt)
        #pragma unroll
        for (int r = 0; r < 4; ++r) mx = fmaxf(mx, s[mt][r]);
      mx = fmaxf(mx, __shfl_xor(mx, 16)); mx = fmaxf(mx, __shfl_xor(mx, 32));
      float e[4][4]; float sum = 0.f;
      #pragma unroll
      for (int mt = 0; mt < 4; ++mt)
        #pragma unroll
        for (int r = 0; r < 4; ++r) { e[mt][r] = __expf(s[mt][r] - mx); sum += e[mt][r]; }
      sum += __shfl_xor(sum, 16); sum += __shfl_xor(sum, 32);
      inv_s[nt] = 1.f / sum;
      #pragma unroll
      for (int mt = 0; mt < 4; ++mt)
        pf[mt][nt] = pk4(e[mt][0], e[mt][1], e[mt][2], e[mt][3]);
    }

    // ---- V pass (x32): v = x * Wv'^T (+bias) -> vf frags ----
    half4v vf[4][2];
    {
      f32x4 acc[4][2];
      #pragma unroll
      for (int tt = 0; tt < 4; ++tt) { acc[tt][0] = zf; acc[tt][1] = zf; }
      #pragma unroll
      for (int ks = 0; ks < 3; ++ks) {
        half8v xf[4];
        #pragma unroll
        for (int tt = 0; tt < 4; ++tt)
          xf[tt] = *(const half8v*)(xo + (16*tt+llo)*200 + half*96 + 32*ks + 8*lhi);
        #pragma unroll
        for (int ct = 0; ct < 2; ++ct) {
          half8v wvf = *(const half8v*)(ws + (size_t)(((4+half)*6 + 2*(h%3)+ct)*3 + ks)*1024 + lane*16);
          #pragma unroll
          for (int tt = 0; tt < 4; ++tt)
            acc[tt][ct] = __builtin_amdgcn_mfma_f32_16x16x32_f16(xf[tt], wvf, acc[tt][ct], 0,0,0);
        }
      }
      const float* vbp = half ? v2b : v1b;
      #pragma unroll
      for (int ct = 0; ct < 2; ++ct) {
        float vb = vbp[hd0 + 16*ct + llo];
        #pragma unroll
        for (int tt = 0; tt < 4; ++tt)
          vf[tt][ct] = pk4(acc[tt][ct][0] + vb, acc[tt][ct][1] + vb,
                           acc[tt][ct][2] + vb, acc[tt][ct][3] + vb);
      }
    }

    // ---- o^T = V^T * P^T (x16, all-register), normalize at store -> ob (separate buffer) ----
    f32x4 oacc[2][4];
    #pragma unroll
    for (int dt = 0; dt < 2; ++dt)
      #pragma unroll
      for (int nt = 0; nt < 4; ++nt) oacc[dt][nt] = zf;
    __builtin_amdgcn_s_setprio(1);
    #pragma unroll
    for (int mt = 0; mt < 4; ++mt)
      #pragma unroll
      for (int dt = 0; dt < 2; ++dt)
        #pragma unroll
        for (int nt = 0; nt < 4; ++nt)
          oacc[dt][nt] = __builtin_amdgcn_mfma_f32_16x16x16f16(vf[mt][dt], pf[mt][nt], oacc[dt][nt], 0,0,0);
    __builtin_amdgcn_s_setprio(0);
    // write o to ob immediately (own-head columns; nobody else touches them before [C])
    #pragma unroll
    for (int dt = 0; dt < 2; ++dt)
      #pragma unroll
      for (int nt = 0; nt < 4; ++nt)
        *(half4v*)(ob + (16*nt+llo)*200 + 32*h + 16*dt + 4*lhi) =
          pk4(oacc[dt][nt][0]*inv_s[nt], oacc[dt][nt][1]*inv_s[nt],
              oacc[dt][nt][2]*inv_s[nt], oacc[dt][nt][3]*inv_s[nt]);

    __syncthreads();   // [C] o complete; all xo reads (QK,V) retired

    // ---- issue next window's x loads (live only through proj: ~112 reg peak) ----
    float4v xv[8];
    if (i < NITER-1) {
      const float* xgn = x + (size_t)(b + 2) * (NT*DM);
      #pragma unroll
      for (int it = 0; it < 8; ++it) xv[it] = *(const float4v*)(xgn + 4*(lt + it*384));
    }

    // ---- final^T = Wp * o^T (x32) from ob ; wave -> (half, c-tile pair) ----
    {
      const int ph = h & 1;
      const int cp = h >> 1;          // 0..2
      f32x4 facc[2][4];
      #pragma unroll
      for (int cc = 0; cc < 2; ++cc)
        #pragma unroll
        for (int nt = 0; nt < 4; ++nt) facc[cc][nt] = zf;
      #pragma unroll
      for (int ks = 0; ks < 3; ++ks) {
        half8v of[4];
        #pragma unroll
        for (int nt = 0; nt < 4; ++nt)
          of[nt] = *(const half8v*)(ob + (16*nt+llo)*200 + 96*ph + 32*ks + 8*lhi);
        #pragma unroll
        for (int cc = 0; cc < 2; ++cc) {
          half8v wp = *(const half8v*)(ws + (size_t)(((6+ph)*6 + 2*cp+cc)*3 + ks)*1024 + lane*16);
          #pragma unroll
          for (int nt = 0; nt < 4; ++nt)
            facc[cc][nt] = __builtin_amdgcn_mfma_f32_16x16x32_f16(wp, of[nt], facc[cc][nt], 0,0,0);
        }
      }
      const float* pbp = ph ? p2b : p1b;
      float* og = out + (size_t)b * (NT*DM);
      #pragma unroll
      for (int cc = 0; cc < 2; ++cc) {
        float4v pb = *(const float4v*)(pbp + 16*(2*cp+cc) + 4*lhi);
        #pragma unroll
        for (int nt = 0; nt < 4; ++nt) {
          float4v res;
          #pragma unroll
          for (int r = 0; r < 4; ++r) res[r] = facc[cc][nt][r] + pb[r];
          *(float4v*)(og + (size_t)(16*nt+llo)*192 + 96*ph + 16*(2*cp+cc) + 4*lhi) = res;
        }
      }
    }

    // ---- stage next x into xo (xo free since [C]; loads had proj to land) ----
    if (i < NITER-1) {
      #pragma unroll
      for (int it = 0; it < 8; ++it) {
        int f4 = lt + it*384;
        int row = f4 / 48, c4 = f4 % 48;
        *(half4v*)(xo + row*200 + c4*4) = pk4(xv[it][0], xv[it][1], xv[it][2], xv[it][3]);
      }
    }
    __syncthreads();   // [A] next x staged; ob reads retired
  }
}

extern "C" void kernel_launch(void* const* d_in, const int* in_sizes, int n_in,
                              void* d_out, int out_size, void* d_ws, size_t ws_size,
                              hipStream_t stream)
{
  const float* x    = (const float*)d_in[0];
  const float* mask = (const float*)d_in[1];
  const float* ls   = (const float*)d_in[2];
  const float* w1   = (const float*)d_in[3];
  const float* b1   = (const float*)d_in[4];
  const float* w2   = (const float*)d_in[5];
  const float* q1w  = (const float*)d_in[6];  const float* q1b = (const float*)d_in[7];
  const float* q2w  = (const float*)d_in[8];  const float* q2b = (const float*)d_in[9];
  const float* k1w  = (const float*)d_in[10]; const float* k1b = (const float*)d_in[11];
  const float* k2w  = (const float*)d_in[12]; const float* k2b = (const float*)d_in[13];
  const float* v1w  = (const float*)d_in[14]; const float* v1b = (const float*)d_in[15];
  const float* v2w  = (const float*)d_in[16]; const float* v2b = (const float*)d_in[17];
  const float* p1w  = (const float*)d_in[18]; const float* p1b = (const float*)d_in[19];
  const float* p2w  = (const float*)d_in[20]; const float* p2b = (const float*)d_in[21];
  const float* rpbt = (const float*)d_in[22];
  const int*   rpi  = (const int*)d_in[23];
  char* ws = (char*)d_ws;
  float* o = (float*)d_out;

  pre_a<<<49, 384, 0, stream>>>(q1w,q2w,k1w,k2w,v1w,v2w,p1w,p2w, w1,b1,w2, rpbt, ls, ws);
  pre_b<<<384, 256, 0, stream>>>(mask, rpi, ws);

  hipFuncSetAttribute((const void*)win_attn,
                      hipFuncAttributeMaxDynamicSharedMemorySize, 102400);
  win_attn<<<256, 768, 102400, stream>>>(x, ws, q1b,q2b,k1b,k2b,v1b,v2b,p1b,p2b, o);
}

// Round 14
// 202.759 us; speedup vs baseline: 1.7373x; 1.6505x over previous
//
#include <hip/hip_runtime.h>
#include <hip/hip_bf16.h>

#define NT 64
#define DM 192
#define LOG2E 1.4426950408889634f

typedef __attribute__((ext_vector_type(4))) float f32x4;
typedef __attribute__((ext_vector_type(4))) float float4v;
using half2v = __attribute__((ext_vector_type(2))) _Float16;
using half4v = __attribute__((ext_vector_type(4))) _Float16;
using half8v = __attribute__((ext_vector_type(8))) _Float16;

// ws layout (bytes)
#define BIAS_OFF  147456      // 8*6*3*1024 W-frags
#define TAB_OFF   6438912     // BIAS_OFF + 384*16*64*16
#define SCALE_OFF 6444312

__device__ __forceinline__ half4v pk4(float a, float b, float c, float d){
  half2v lo = __builtin_bit_cast(half2v, __builtin_amdgcn_cvt_pkrtz(a, b));
  half2v hi = __builtin_bit_cast(half2v, __builtin_amdgcn_cvt_pkrtz(c, d));
  half4v r; r[0]=lo[0]; r[1]=lo[1]; r[2]=hi[0]; r[3]=hi[1];
  return r;
}
// native 2^x (v_exp_f32 is exp2); HW interlocks cover trans latency
__device__ __forceinline__ float exp2v(float x){
  float r;
  asm("v_exp_f32 %0, %1" : "=v"(r) : "v"(x));
  return r;
}

// ---------------- precompute A: W frags in 16x16x32 layout + rpb-mlp table + scales ----------------
// frag(mat, ct, ks): lane holds W'[16ct + (lane&15)][32ks + 8*(lane>>4) + j], j=0..7 (f16).
// Residual fold: q/k/v weights (mats 0..5) get +I. Scales pre-multiplied by log2(e).
__global__ __launch_bounds__(384) void pre_a(
  const float* __restrict__ q1w, const float* __restrict__ q2w,
  const float* __restrict__ k1w, const float* __restrict__ k2w,
  const float* __restrict__ v1w, const float* __restrict__ v2w,
  const float* __restrict__ p1w, const float* __restrict__ p2w,
  const float* __restrict__ w1, const float* __restrict__ b1,
  const float* __restrict__ w2, const float* __restrict__ rpbt,
  const float* __restrict__ ls, char* __restrict__ ws)
{
  int blk = blockIdx.x, t = threadIdx.x;
  if (blk < 48) {
    const float* Ws[8] = {q1w,q2w,k1w,k2w,v1w,v2w,p1w,p2w};
    int mat = blk / 6, ct = blk % 6;
    int lane = t & 63, ks = t >> 6;        // ks 0..5, only 0..2 used
    if (ks < 3) {
      const float* W = Ws[mat];
      int c  = 16*ct + (lane & 15);
      int d0 = 32*ks + 8*(lane >> 4);
      half8v h;
      #pragma unroll
      for (int j = 0; j < 8; ++j) {
        float wel = W[c*96 + d0 + j];
        if (mat < 6 && c == d0 + j) wel += 1.0f;   // fold residual identity
        h[j] = (_Float16)wel;
      }
      *(half8v*)(ws + (size_t)((mat*6+ct)*3+ks)*1024 + lane*16) = h;
    }
  } else {
    float* tab = (float*)(ws + TAB_OFF);
    if (t < 225) {
      float t0 = rpbt[2*t], t1 = rpbt[2*t+1];
      float acc[6] = {0,0,0,0,0,0};
      for (int j = 0; j < 128; ++j) {
        float hv = fmaxf(t0*w1[2*j] + t1*w1[2*j+1] + b1[j], 0.f);
        #pragma unroll
        for (int hh = 0; hh < 6; ++hh) acc[hh] += hv * w2[hh*128 + j];
      }
      #pragma unroll
      for (int hh = 0; hh < 6; ++hh) tab[t*6 + hh] = acc[hh];
    }
    if (t >= 240 && t < 246) {
      float* sc = (float*)(ws + SCALE_OFF);
      int i = t - 240;
      sc[i] = expf(fminf(ls[i], 4.605170185988091f)) * LOG2E; // log(100); exp2-folded
    }
  }
}

// ---------------- precompute B: bias = log2e*(16*sigmoid(rpb)+mask) in S^T fragment order ----------------
__global__ __launch_bounds__(256) void pre_b(
  const float* __restrict__ mask, const int* __restrict__ rpi,
  char* __restrict__ ws)
{
  int w = blockIdx.x / 6, h = blockIdx.x % 6;
  int lane = threadIdx.x & 63, nt = threadIdx.x >> 6;
  const float* tab = (const float*)(ws + TAB_OFF);
  float* bias = (float*)(ws + BIAS_OFF);
  #pragma unroll
  for (int mt = 0; mt < 4; ++mt)
    #pragma unroll
    for (int r = 0; r < 4; ++r) {
      int m = 16*mt + ((lane >> 4) << 2) + r;
      int n = 16*nt + (lane & 15);
      int idx = rpi[n*64 + m];
      float tv = tab[idx*6 + h];
      float sg = 16.f / (1.f + expf(-tv));
      float mv = mask[(w*64 + n)*64 + m];
      bias[(size_t)(((w*6+h)*4+mt)*4+nt)*256 + lane*4 + r] = (sg + mv) * LOG2E;
    }
}

// ---------------- main fused kernel: 1 block = 2 windows, 12 waves = 2 x (6 heads) ----------------
// r11 structure + VALU diet: biases ride in MFMA accumulator init / C operand; softmax in exp2
// domain (scale & bias pre-multiplied by log2e, raw v_exp_f32).
__global__ __launch_bounds__(768, 2) void win_attn(
  const float* __restrict__ x, const char* __restrict__ ws,
  const float* __restrict__ q1b, const float* __restrict__ q2b,
  const float* __restrict__ k1b, const float* __restrict__ k2b,
  const float* __restrict__ v1b, const float* __restrict__ v2b,
  const float* __restrict__ p1b, const float* __restrict__ p2b,
  float* __restrict__ out)
{
  __shared__ __align__(16) _Float16 xo2[2][64*200];   // per-window x (f16), later o overlay
  const int tid = threadIdx.x;
  const int wv = tid >> 6, lane = tid & 63;
  const int llo = lane & 15, lhi = lane >> 4;
  const int wgrp = (wv >= 6) ? 1 : 0;   // which window in this block
  const int h = wv - 6*wgrp;            // head 0..5
  const int b = blockIdx.x*2 + wgrp, w_in = b & 63;
  const int lt = tid - 384*wgrp;        // thread id within window group (0..383)
  _Float16* xo = xo2[wgrp];
  const int half = (h < 3) ? 0 : 1;
  const int hd0 = 32 * (h % 3);                   // head-dim base within half
  const f32x4 zf = {0.f,0.f,0.f,0.f};
  const float* xg = x + (size_t)b * (NT*DM);

  // ---- stage x -> LDS f16 (coalesced float4 loads, packed cvt, 8B stores) ----
  float4v xv[8];
  #pragma unroll
  for (int it = 0; it < 8; ++it) xv[it] = *(const float4v*)(xg + 4*(lt + it*384));
  #pragma unroll
  for (int it = 0; it < 8; ++it) {
    int f4 = lt + it*384;
    int row = f4 / 48, c4 = f4 % 48;
    *(half4v*)(xo + row*200 + c4*4) = pk4(xv[it][0], xv[it][1], xv[it][2], xv[it][3]);
  }
  __syncthreads();   // (1) x staged

  const float scale_h = ((const float*)(ws + SCALE_OFF))[h];

  // ---- joint QK pass (x32): acc init = bias fragment; l2norm -> qf/kf frags ----
  half4v qf[2][4], kf[2][4];
  {
    const float* qbp = half ? q2b : q1b;
    const float* kbp = half ? k2b : k1b;
    f32x4 qacc[2][4], kacc[2][4];
    #pragma unroll
    for (int dt = 0; dt < 2; ++dt) {
      f32x4 qb = *(const f32x4*)(qbp + hd0 + 16*dt + 4*lhi);
      f32x4 kb = *(const f32x4*)(kbp + hd0 + 16*dt + 4*lhi);
      #pragma unroll
      for (int tt = 0; tt < 4; ++tt) { qacc[dt][tt] = qb; kacc[dt][tt] = kb; }
    }
    __builtin_amdgcn_s_setprio(1);
    #pragma unroll
    for (int ks = 0; ks < 3; ++ks) {
      half8v xf[4];
      #pragma unroll
      for (int tt = 0; tt < 4; ++tt)
        xf[tt] = *(const half8v*)(xo + (16*tt+llo)*200 + half*96 + 32*ks + 8*lhi);
      #pragma unroll
      for (int dt = 0; dt < 2; ++dt) {
        half8v wq = *(const half8v*)(ws + (size_t)(((0+half)*6 + 2*(h%3)+dt)*3 + ks)*1024 + lane*16);
        half8v wk = *(const half8v*)(ws + (size_t)(((2+half)*6 + 2*(h%3)+dt)*3 + ks)*1024 + lane*16);
        #pragma unroll
        for (int tt = 0; tt < 4; ++tt) {
          qacc[dt][tt] = __builtin_amdgcn_mfma_f32_16x16x32_f16(wq, xf[tt], qacc[dt][tt], 0,0,0);
          kacc[dt][tt] = __builtin_amdgcn_mfma_f32_16x16x32_f16(wk, xf[tt], kacc[dt][tt], 0,0,0);
        }
      }
    }
    __builtin_amdgcn_s_setprio(0);
    #pragma unroll
    for (int tt = 0; tt < 4; ++tt) {
      float sq = 0.f, sk = 0.f;
      #pragma unroll
      for (int dt = 0; dt < 2; ++dt)
        #pragma unroll
        for (int r = 0; r < 4; ++r) {
          sq += qacc[dt][tt][r]*qacc[dt][tt][r];
          sk += kacc[dt][tt][r]*kacc[dt][tt][r];
        }
      sq += __shfl_xor(sq, 16); sq += __shfl_xor(sq, 32);
      sk += __shfl_xor(sk, 16); sk += __shfl_xor(sk, 32);
      float invq = scale_h / fmaxf(sqrtf(sq), 1e-12f);   // logit scale * log2e folded
      float invk = 1.f / fmaxf(sqrtf(sk), 1e-12f);
      #pragma unroll
      for (int dt = 0; dt < 2; ++dt) {
        qf[dt][tt] = pk4(qacc[dt][tt][0]*invq, qacc[dt][tt][1]*invq,
                         qacc[dt][tt][2]*invq, qacc[dt][tt][3]*invq);
        kf[dt][tt] = pk4(kacc[dt][tt][0]*invk, kacc[dt][tt][1]*invk,
                         kacc[dt][tt][2]*invk, kacc[dt][tt][3]*invk);
      }
    }
  }

  // ---- S^T = kn*qn^T + bias (bias as MFMA C operand), softmax in exp2 domain ----
  const float4v* biasf = (const float4v*)(ws + BIAS_OFF);
  half4v pf[4][4];
  float inv_s[4];
  #pragma unroll
  for (int nt = 0; nt < 4; ++nt) {
    f32x4 s[4];
    #pragma unroll
    for (int mt = 0; mt < 4; ++mt) {
      f32x4 bb = *(const f32x4*)&biasf[(size_t)(((w_in*6 + h)*4 + mt)*4 + nt)*64 + lane];
      f32x4 t0 = __builtin_amdgcn_mfma_f32_16x16x16f16(kf[0][mt], qf[0][nt], bb, 0,0,0);
      s[mt]    = __builtin_amdgcn_mfma_f32_16x16x16f16(kf[1][mt], qf[1][nt], t0, 0,0,0);
    }
    float mx = s[0][0];
    #pragma unroll
    for (int mt = 0; mt < 4; ++mt)
      #pragma unroll
      for (int r = 0; r < 4; ++r) mx = fmaxf(mx, s[mt][r]);
    mx = fmaxf(mx, __shfl_xor(mx, 16)); mx = fmaxf(mx, __shfl_xor(mx, 32));
    float e[4][4]; float sum = 0.f;
    #pragma unroll
    for (int mt = 0; mt < 4; ++mt)
      #pragma unroll
      for (int r = 0; r < 4; ++r) { e[mt][r] = exp2v(s[mt][r] - mx); sum += e[mt][r]; }
    sum += __shfl_xor(sum, 16); sum += __shfl_xor(sum, 32);
    inv_s[nt] = 1.f / sum;
    #pragma unroll
    for (int mt = 0; mt < 4; ++mt)
      pf[mt][nt] = pk4(e[mt][0], e[mt][1], e[mt][2], e[mt][3]);
  }

  // ---- V pass (x32): acc init = bias splat -> vf frags ----
  half4v vf[4][2];
  {
    const float* vbp = half ? v2b : v1b;
    f32x4 acc[4][2];
    #pragma unroll
    for (int ct = 0; ct < 2; ++ct) {
      float vb = vbp[hd0 + 16*ct + llo];
      f32x4 vbv = {vb, vb, vb, vb};
      #pragma unroll
      for (int tt = 0; tt < 4; ++tt) acc[tt][ct] = vbv;
    }
    #pragma unroll
    for (int ks = 0; ks < 3; ++ks) {
      half8v xf[4];
      #pragma unroll
      for (int tt = 0; tt < 4; ++tt)
        xf[tt] = *(const half8v*)(xo + (16*tt+llo)*200 + half*96 + 32*ks + 8*lhi);
      #pragma unroll
      for (int ct = 0; ct < 2; ++ct) {
        half8v wvf = *(const half8v*)(ws + (size_t)(((4+half)*6 + 2*(h%3)+ct)*3 + ks)*1024 + lane*16);
        #pragma unroll
        for (int tt = 0; tt < 4; ++tt)
          acc[tt][ct] = __builtin_amdgcn_mfma_f32_16x16x32_f16(xf[tt], wvf, acc[tt][ct], 0,0,0);
      }
    }
    #pragma unroll
    for (int ct = 0; ct < 2; ++ct)
      #pragma unroll
      for (int tt = 0; tt < 4; ++tt)
        vf[tt][ct] = pk4(acc[tt][ct][0], acc[tt][ct][1], acc[tt][ct][2], acc[tt][ct][3]);
  }

  // ---- o^T = V^T * P^T (x16, all-register), normalize at store ----
  f32x4 oacc[2][4];
  #pragma unroll
  for (int dt = 0; dt < 2; ++dt)
    #pragma unroll
    for (int nt = 0; nt < 4; ++nt) oacc[dt][nt] = zf;
  __builtin_amdgcn_s_setprio(1);
  #pragma unroll
  for (int mt = 0; mt < 4; ++mt)
    #pragma unroll
    for (int dt = 0; dt < 2; ++dt)
      #pragma unroll
      for (int nt = 0; nt < 4; ++nt)
        oacc[dt][nt] = __builtin_amdgcn_mfma_f32_16x16x16f16(vf[mt][dt], pf[mt][nt], oacc[dt][nt], 0,0,0);
  __builtin_amdgcn_s_setprio(0);

  __syncthreads();   // (2) all waves done reading x
  #pragma unroll
  for (int dt = 0; dt < 2; ++dt)
    #pragma unroll
    for (int nt = 0; nt < 4; ++nt)
      *(half4v*)(xo + (16*nt+llo)*200 + 32*h + 16*dt + 4*lhi) =
        pk4(oacc[dt][nt][0]*inv_s[nt], oacc[dt][nt][1]*inv_s[nt],
            oacc[dt][nt][2]*inv_s[nt], oacc[dt][nt][3]*inv_s[nt]);
  __syncthreads();   // (3) o complete

  // ---- final^T = Wp * o^T (x32); acc init = proj bias; wave -> (half, c-tile pair) ----
  const int ph = h & 1;
  const int cp = h >> 1;          // 0..2
  const float* pbp = ph ? p2b : p1b;
  f32x4 facc[2][4];
  #pragma unroll
  for (int cc = 0; cc < 2; ++cc) {
    f32x4 pb = *(const f32x4*)(pbp + 16*(2*cp+cc) + 4*lhi);
    #pragma unroll
    for (int nt = 0; nt < 4; ++nt) facc[cc][nt] = pb;
  }
  #pragma unroll
  for (int ks = 0; ks < 3; ++ks) {
    half8v of[4];
    #pragma unroll
    for (int nt = 0; nt < 4; ++nt)
      of[nt] = *(const half8v*)(xo + (16*nt+llo)*200 + 96*ph + 32*ks + 8*lhi);
    #pragma unroll
    for (int cc = 0; cc < 2; ++cc) {
      half8v wp = *(const half8v*)(ws + (size_t)(((6+ph)*6 + 2*cp+cc)*3 + ks)*1024 + lane*16);
      #pragma unroll
      for (int nt = 0; nt < 4; ++nt)
        facc[cc][nt] = __builtin_amdgcn_mfma_f32_16x16x32_f16(wp, of[nt], facc[cc][nt], 0,0,0);
    }
  }
  float* og = out + (size_t)b * (NT*DM);
  #pragma unroll
  for (int cc = 0; cc < 2; ++cc)
    #pragma unroll
    for (int nt = 0; nt < 4; ++nt) {
      float4v res = {facc[cc][nt][0], facc[cc][nt][1], facc[cc][nt][2], facc[cc][nt][3]};
      *(float4v*)(og + (size_t)(16*nt+llo)*192 + 96*ph + 16*(2*cp+cc) + 4*lhi) = res;
    }
}

extern "C" void kernel_launch(void* const* d_in, const int* in_sizes, int n_in,
                              void* d_out, int out_size, void* d_ws, size_t ws_size,
                              hipStream_t stream)
{
  const float* x    = (const float*)d_in[0];
  const float* mask = (const float*)d_in[1];
  const float* ls   = (const float*)d_in[2];
  const float* w1   = (const float*)d_in[3];
  const float* b1   = (const float*)d_in[4];
  const float* w2   = (const float*)d_in[5];
  const float* q1w  = (const float*)d_in[6];  const float* q1b = (const float*)d_in[7];
  const float* q2w  = (const float*)d_in[8];  const float* q2b = (const float*)d_in[9];
  const float* k1w  = (const float*)d_in[10]; const float* k1b = (const float*)d_in[11];
  const float* k2w  = (const float*)d_in[12]; const float* k2b = (const float*)d_in[13];
  const float* v1w  = (const float*)d_in[14]; const float* v1b = (const float*)d_in[15];
  const float* v2w  = (const float*)d_in[16]; const float* v2b = (const float*)d_in[17];
  const float* p1w  = (const float*)d_in[18]; const float* p1b = (const float*)d_in[19];
  const float* p2w  = (const float*)d_in[20]; const float* p2b = (const float*)d_in[21];
  const float* rpbt = (const float*)d_in[22];
  const int*   rpi  = (const int*)d_in[23];
  char* ws = (char*)d_ws;
  float* o = (float*)d_out;

  pre_a<<<49, 384, 0, stream>>>(q1w,q2w,k1w,k2w,v1w,v2w,p1w,p2w, w1,b1,w2, rpbt, ls, ws);
  pre_b<<<384, 256, 0, stream>>>(mask, rpi, ws);
  win_attn<<<2048, 768, 0, stream>>>(x, ws, q1b,q2b,k1b,k2b,v1b,v2b,p1b,p2b, o);
}

// Round 16
// 197.411 us; speedup vs baseline: 1.7843x; 1.0271x over previous
//
#include <hip/hip_runtime.h>
#include <hip/hip_bf16.h>

#define NT 64
#define DM 192
#define LOG2E 1.4426950408889634f

typedef __attribute__((ext_vector_type(4))) float f32x4;
typedef __attribute__((ext_vector_type(4))) float float4v;
using half2v = __attribute__((ext_vector_type(2))) _Float16;
using half4v = __attribute__((ext_vector_type(4))) _Float16;
using half8v = __attribute__((ext_vector_type(8))) _Float16;

// ws layout (bytes)
#define BIAS_OFF  147456      // 8*6*3*1024 W-frags
#define TAB_OFF   6438912     // BIAS_OFF + 384*16*64*16
#define SCALE_OFF 6444312

__device__ __forceinline__ half4v pk4(float a, float b, float c, float d){
  half2v lo = __builtin_bit_cast(half2v, __builtin_amdgcn_cvt_pkrtz(a, b));
  half2v hi = __builtin_bit_cast(half2v, __builtin_amdgcn_cvt_pkrtz(c, d));
  half4v r; r[0]=lo[0]; r[1]=lo[1]; r[2]=hi[0]; r[3]=hi[1];
  return r;
}
// native 2^x (v_exp_f32 is exp2)
__device__ __forceinline__ float exp2v(float x){
  float r;
  asm("v_exp_f32 %0, %1" : "=v"(r) : "v"(x));
  return r;
}

// ---------------- precompute A: W frags in 16x16x32 layout + rpb-mlp table + scales ----------------
__global__ __launch_bounds__(384) void pre_a(
  const float* __restrict__ q1w, const float* __restrict__ q2w,
  const float* __restrict__ k1w, const float* __restrict__ k2w,
  const float* __restrict__ v1w, const float* __restrict__ v2w,
  const float* __restrict__ p1w, const float* __restrict__ p2w,
  const float* __restrict__ w1, const float* __restrict__ b1,
  const float* __restrict__ w2, const float* __restrict__ rpbt,
  const float* __restrict__ ls, char* __restrict__ ws)
{
  int blk = blockIdx.x, t = threadIdx.x;
  if (blk < 48) {
    const float* Ws[8] = {q1w,q2w,k1w,k2w,v1w,v2w,p1w,p2w};
    int mat = blk / 6, ct = blk % 6;
    int lane = t & 63, ks = t >> 6;        // ks 0..5, only 0..2 used
    if (ks < 3) {
      const float* W = Ws[mat];
      int c  = 16*ct + (lane & 15);
      int d0 = 32*ks + 8*(lane >> 4);
      half8v h;
      #pragma unroll
      for (int j = 0; j < 8; ++j) {
        float wel = W[c*96 + d0 + j];
        if (mat < 6 && c == d0 + j) wel += 1.0f;   // fold residual identity
        h[j] = (_Float16)wel;
      }
      *(half8v*)(ws + (size_t)((mat*6+ct)*3+ks)*1024 + lane*16) = h;
    }
  } else {
    float* tab = (float*)(ws + TAB_OFF);
    if (t < 225) {
      float t0 = rpbt[2*t], t1 = rpbt[2*t+1];
      float acc[6] = {0,0,0,0,0,0};
      for (int j = 0; j < 128; ++j) {
        float hv = fmaxf(t0*w1[2*j] + t1*w1[2*j+1] + b1[j], 0.f);
        #pragma unroll
        for (int hh = 0; hh < 6; ++hh) acc[hh] += hv * w2[hh*128 + j];
      }
      #pragma unroll
      for (int hh = 0; hh < 6; ++hh) tab[t*6 + hh] = acc[hh];
    }
    if (t >= 240 && t < 246) {
      float* sc = (float*)(ws + SCALE_OFF);
      int i = t - 240;
      sc[i] = expf(fminf(ls[i], 4.605170185988091f)) * LOG2E; // log(100); exp2-folded
    }
  }
}

// ---------------- precompute B: bias = log2e*(16*sigmoid(rpb)+mask) in S^T fragment order ----------------
__global__ __launch_bounds__(256) void pre_b(
  const float* __restrict__ mask, const int* __restrict__ rpi,
  char* __restrict__ ws)
{
  int w = blockIdx.x / 6, h = blockIdx.x % 6;
  int lane = threadIdx.x & 63, nt = threadIdx.x >> 6;
  const float* tab = (const float*)(ws + TAB_OFF);
  float* bias = (float*)(ws + BIAS_OFF);
  #pragma unroll
  for (int mt = 0; mt < 4; ++mt)
    #pragma unroll
    for (int r = 0; r < 4; ++r) {
      int m = 16*mt + ((lane >> 4) << 2) + r;
      int n = 16*nt + (lane & 15);
      int idx = rpi[n*64 + m];
      float tv = tab[idx*6 + h];
      float sg = 16.f / (1.f + expf(-tv));
      float mv = mask[(w*64 + n)*64 + m];
      bias[(size_t)(((w*6+h)*4+mt)*4+nt)*256 + lane*4 + r] = (sg + mv) * LOG2E;
    }
}

// ---------------- main fused kernel: 1 block = 2 windows, 12 waves = 2 x (6 heads) ----------------
// r14 structure + (1) XCD-swizzled block mapping so each XCD's 8 w_in bias slices stay
// L2-resident (768KB < 4MB, vs 6.3MB thrash), (2) tree-shaped reductions (chain depth 16->4),
// (3) rsq/rcp approx intrinsics, (4) setprio around S and V MFMA clusters.
__global__ __launch_bounds__(768, 2) void win_attn(
  const float* __restrict__ x, const char* __restrict__ ws,
  const float* __restrict__ q1b, const float* __restrict__ q2b,
  const float* __restrict__ k1b, const float* __restrict__ k2b,
  const float* __restrict__ v1b, const float* __restrict__ v2b,
  const float* __restrict__ p1b, const float* __restrict__ p2b,
  float* __restrict__ out)
{
  __shared__ __align__(16) _Float16 xo2[2][64*200];   // per-window x (f16), later o overlay
  const int tid = threadIdx.x;
  const int wv = tid >> 6, lane = tid & 63;
  const int llo = lane & 15, lhi = lane >> 4;
  const int wgrp = (wv >= 6) ? 1 : 0;   // which window in this block
  const int h = wv - 6*wgrp;            // head 0..5
  // XCD swizzle: group g = b0%32 determines the w_in pair; keep each g on one XCD (B%8).
  // B = 8*((g>>3)*64 + k) + (g&7)  <=>  g = ((B>>3)>>6)*8 + (B&7), k = (B>>3)&63, b0 = k*32+g.
  const int B = blockIdx.x;
  const int g = (((B >> 3) >> 6) << 3) | (B & 7);
  const int kk = (B >> 3) & 63;
  const int b0 = kk*32 + g;
  const int b = b0*2 + wgrp, w_in = b & 63;
  const int lt = tid - 384*wgrp;        // thread id within window group (0..383)
  _Float16* xo = xo2[wgrp];
  const int half = (h < 3) ? 0 : 1;
  const int hd0 = 32 * (h % 3);                   // head-dim base within half
  const f32x4 zf = {0.f,0.f,0.f,0.f};
  const float* xg = x + (size_t)b * (NT*DM);

  // ---- stage x -> LDS f16 (coalesced float4 loads, packed cvt, 8B stores) ----
  float4v xv[8];
  #pragma unroll
  for (int it = 0; it < 8; ++it) xv[it] = *(const float4v*)(xg + 4*(lt + it*384));
  #pragma unroll
  for (int it = 0; it < 8; ++it) {
    int f4 = lt + it*384;
    int row = f4 / 48, c4 = f4 % 48;
    *(half4v*)(xo + row*200 + c4*4) = pk4(xv[it][0], xv[it][1], xv[it][2], xv[it][3]);
  }
  __syncthreads();   // (1) x staged

  const float scale_h = ((const float*)(ws + SCALE_OFF))[h];

  // ---- joint QK pass (x32): acc init = bias fragment; l2norm (tree) -> qf/kf frags ----
  half4v qf[2][4], kf[2][4];
  {
    const float* qbp = half ? q2b : q1b;
    const float* kbp = half ? k2b : k1b;
    f32x4 qacc[2][4], kacc[2][4];
    #pragma unroll
    for (int dt = 0; dt < 2; ++dt) {
      f32x4 qb = *(const f32x4*)(qbp + hd0 + 16*dt + 4*lhi);
      f32x4 kb = *(const f32x4*)(kbp + hd0 + 16*dt + 4*lhi);
      #pragma unroll
      for (int tt = 0; tt < 4; ++tt) { qacc[dt][tt] = qb; kacc[dt][tt] = kb; }
    }
    __builtin_amdgcn_s_setprio(1);
    #pragma unroll
    for (int ks = 0; ks < 3; ++ks) {
      half8v xf[4];
      #pragma unroll
      for (int tt = 0; tt < 4; ++tt)
        xf[tt] = *(const half8v*)(xo + (16*tt+llo)*200 + half*96 + 32*ks + 8*lhi);
      #pragma unroll
      for (int dt = 0; dt < 2; ++dt) {
        half8v wq = *(const half8v*)(ws + (size_t)(((0+half)*6 + 2*(h%3)+dt)*3 + ks)*1024 + lane*16);
        half8v wk = *(const half8v*)(ws + (size_t)(((2+half)*6 + 2*(h%3)+dt)*3 + ks)*1024 + lane*16);
        #pragma unroll
        for (int tt = 0; tt < 4; ++tt) {
          qacc[dt][tt] = __builtin_amdgcn_mfma_f32_16x16x32_f16(wq, xf[tt], qacc[dt][tt], 0,0,0);
          kacc[dt][tt] = __builtin_amdgcn_mfma_f32_16x16x32_f16(wk, xf[tt], kacc[dt][tt], 0,0,0);
        }
      }
    }
    __builtin_amdgcn_s_setprio(0);
    #pragma unroll
    for (int tt = 0; tt < 4; ++tt) {
      f32x4 q0 = qacc[0][tt], q1 = qacc[1][tt];
      f32x4 k0 = kacc[0][tt], k1 = kacc[1][tt];
      float sq = ((q0[0]*q0[0] + q0[1]*q0[1]) + (q0[2]*q0[2] + q0[3]*q0[3]))
               + ((q1[0]*q1[0] + q1[1]*q1[1]) + (q1[2]*q1[2] + q1[3]*q1[3]));
      float sk = ((k0[0]*k0[0] + k0[1]*k0[1]) + (k0[2]*k0[2] + k0[3]*k0[3]))
               + ((k1[0]*k1[0] + k1[1]*k1[1]) + (k1[2]*k1[2] + k1[3]*k1[3]));
      sq += __shfl_xor(sq, 16); sq += __shfl_xor(sq, 32);
      sk += __shfl_xor(sk, 16); sk += __shfl_xor(sk, 32);
      float invq = scale_h * __builtin_amdgcn_rsqf(fmaxf(sq, 1e-24f));  // == scale/max(sqrt,1e-12)
      float invk = __builtin_amdgcn_rsqf(fmaxf(sk, 1e-24f));
      qf[0][tt] = pk4(q0[0]*invq, q0[1]*invq, q0[2]*invq, q0[3]*invq);
      qf[1][tt] = pk4(q1[0]*invq, q1[1]*invq, q1[2]*invq, q1[3]*invq);
      kf[0][tt] = pk4(k0[0]*invk, k0[1]*invk, k0[2]*invk, k0[3]*invk);
      kf[1][tt] = pk4(k1[0]*invk, k1[1]*invk, k1[2]*invk, k1[3]*invk);
    }
  }

  // ---- S^T = kn*qn^T + bias (C operand), softmax in exp2 domain, tree reduces ----
  const float4v* biasf = (const float4v*)(ws + BIAS_OFF);
  half4v pf[4][4];
  float inv_s[4];
  #pragma unroll
  for (int nt = 0; nt < 4; ++nt) {
    f32x4 s[4];
    __builtin_amdgcn_s_setprio(1);
    #pragma unroll
    for (int mt = 0; mt < 4; ++mt) {
      f32x4 bb = *(const f32x4*)&biasf[(size_t)(((w_in*6 + h)*4 + mt)*4 + nt)*64 + lane];
      f32x4 t0 = __builtin_amdgcn_mfma_f32_16x16x16f16(kf[0][mt], qf[0][nt], bb, 0,0,0);
      s[mt]    = __builtin_amdgcn_mfma_f32_16x16x16f16(kf[1][mt], qf[1][nt], t0, 0,0,0);
    }
    __builtin_amdgcn_s_setprio(0);
    float m0 = fmaxf(fmaxf(s[0][0], s[0][1]), fmaxf(s[0][2], s[0][3]));
    float m1 = fmaxf(fmaxf(s[1][0], s[1][1]), fmaxf(s[1][2], s[1][3]));
    float m2 = fmaxf(fmaxf(s[2][0], s[2][1]), fmaxf(s[2][2], s[2][3]));
    float m3 = fmaxf(fmaxf(s[3][0], s[3][1]), fmaxf(s[3][2], s[3][3]));
    float mx = fmaxf(fmaxf(m0, m1), fmaxf(m2, m3));
    mx = fmaxf(mx, __shfl_xor(mx, 16)); mx = fmaxf(mx, __shfl_xor(mx, 32));
    float e[4][4];
    #pragma unroll
    for (int mt = 0; mt < 4; ++mt)
      #pragma unroll
      for (int r = 0; r < 4; ++r) e[mt][r] = exp2v(s[mt][r] - mx);
    float t0s = (e[0][0]+e[0][1]) + (e[0][2]+e[0][3]);
    float t1s = (e[1][0]+e[1][1]) + (e[1][2]+e[1][3]);
    float t2s = (e[2][0]+e[2][1]) + (e[2][2]+e[2][3]);
    float t3s = (e[3][0]+e[3][1]) + (e[3][2]+e[3][3]);
    float sum = (t0s+t1s) + (t2s+t3s);
    sum += __shfl_xor(sum, 16); sum += __shfl_xor(sum, 32);
    inv_s[nt] = __builtin_amdgcn_rcpf(sum);   // sum >= 1, approx rcp safe
    #pragma unroll
    for (int mt = 0; mt < 4; ++mt)
      pf[mt][nt] = pk4(e[mt][0], e[mt][1], e[mt][2], e[mt][3]);
  }

  // ---- V pass (x32): acc init = bias splat -> vf frags ----
  half4v vf[4][2];
  {
    const float* vbp = half ? v2b : v1b;
    f32x4 acc[4][2];
    #pragma unroll
    for (int ct = 0; ct < 2; ++ct) {
      float vb = vbp[hd0 + 16*ct + llo];
      f32x4 vbv = {vb, vb, vb, vb};
      #pragma unroll
      for (int tt = 0; tt < 4; ++tt) acc[tt][ct] = vbv;
    }
    __builtin_amdgcn_s_setprio(1);
    #pragma unroll
    for (int ks = 0; ks < 3; ++ks) {
      half8v xf[4];
      #pragma unroll
      for (int tt = 0; tt < 4; ++tt)
        xf[tt] = *(const half8v*)(xo + (16*tt+llo)*200 + half*96 + 32*ks + 8*lhi);
      #pragma unroll
      for (int ct = 0; ct < 2; ++ct) {
        half8v wvf = *(const half8v*)(ws + (size_t)(((4+half)*6 + 2*(h%3)+ct)*3 + ks)*1024 + lane*16);
        #pragma unroll
        for (int tt = 0; tt < 4; ++tt)
          acc[tt][ct] = __builtin_amdgcn_mfma_f32_16x16x32_f16(xf[tt], wvf, acc[tt][ct], 0,0,0);
      }
    }
    __builtin_amdgcn_s_setprio(0);
    #pragma unroll
    for (int ct = 0; ct < 2; ++ct)
      #pragma unroll
      for (int tt = 0; tt < 4; ++tt)
        vf[tt][ct] = pk4(acc[tt][ct][0], acc[tt][ct][1], acc[tt][ct][2], acc[tt][ct][3]);
  }

  // ---- o^T = V^T * P^T (x16, all-register), normalize at store ----
  f32x4 oacc[2][4];
  #pragma unroll
  for (int dt = 0; dt < 2; ++dt)
    #pragma unroll
    for (int nt = 0; nt < 4; ++nt) oacc[dt][nt] = zf;
  __builtin_amdgcn_s_setprio(1);
  #pragma unroll
  for (int mt = 0; mt < 4; ++mt)
    #pragma unroll
    for (int dt = 0; dt < 2; ++dt)
      #pragma unroll
      for (int nt = 0; nt < 4; ++nt)
        oacc[dt][nt] = __builtin_amdgcn_mfma_f32_16x16x16f16(vf[mt][dt], pf[mt][nt], oacc[dt][nt], 0,0,0);
  __builtin_amdgcn_s_setprio(0);

  __syncthreads();   // (2) all waves done reading x
  #pragma unroll
  for (int dt = 0; dt < 2; ++dt)
    #pragma unroll
    for (int nt = 0; nt < 4; ++nt)
      *(half4v*)(xo + (16*nt+llo)*200 + 32*h + 16*dt + 4*lhi) =
        pk4(oacc[dt][nt][0]*inv_s[nt], oacc[dt][nt][1]*inv_s[nt],
            oacc[dt][nt][2]*inv_s[nt], oacc[dt][nt][3]*inv_s[nt]);
  __syncthreads();   // (3) o complete

  // ---- final^T = Wp * o^T (x32); acc init = proj bias; wave -> (half, c-tile pair) ----
  const int ph = h & 1;
  const int cp = h >> 1;          // 0..2
  const float* pbp = ph ? p2b : p1b;
  f32x4 facc[2][4];
  #pragma unroll
  for (int cc = 0; cc < 2; ++cc) {
    f32x4 pb = *(const f32x4*)(pbp + 16*(2*cp+cc) + 4*lhi);
    #pragma unroll
    for (int nt = 0; nt < 4; ++nt) facc[cc][nt] = pb;
  }
  #pragma unroll
  for (int ks = 0; ks < 3; ++ks) {
    half8v of[4];
    #pragma unroll
    for (int nt = 0; nt < 4; ++nt)
      of[nt] = *(const half8v*)(xo + (16*nt+llo)*200 + 96*ph + 32*ks + 8*lhi);
    #pragma unroll
    for (int cc = 0; cc < 2; ++cc) {
      half8v wp = *(const half8v*)(ws + (size_t)(((6+ph)*6 + 2*cp+cc)*3 + ks)*1024 + lane*16);
      #pragma unroll
      for (int nt = 0; nt < 4; ++nt)
        facc[cc][nt] = __builtin_amdgcn_mfma_f32_16x16x32_f16(wp, of[nt], facc[cc][nt], 0,0,0);
    }
  }
  float* og = out + (size_t)b * (NT*DM);
  #pragma unroll
  for (int cc = 0; cc < 2; ++cc)
    #pragma unroll
    for (int nt = 0; nt < 4; ++nt) {
      float4v res = {facc[cc][nt][0], facc[cc][nt][1], facc[cc][nt][2], facc[cc][nt][3]};
      *(float4v*)(og + (size_t)(16*nt+llo)*192 + 96*ph + 16*(2*cp+cc) + 4*lhi) = res;
    }
}

extern "C" void kernel_launch(void* const* d_in, const int* in_sizes, int n_in,
                              void* d_out, int out_size, void* d_ws, size_t ws_size,
                              hipStream_t stream)
{
  const float* x    = (const float*)d_in[0];
  const float* mask = (const float*)d_in[1];
  const float* ls   = (const float*)d_in[2];
  const float* w1   = (const float*)d_in[3];
  const float* b1   = (const float*)d_in[4];
  const float* w2   = (const float*)d_in[5];
  const float* q1w  = (const float*)d_in[6];  const float* q1b = (const float*)d_in[7];
  const float* q2w  = (const float*)d_in[8];  const float* q2b = (const float*)d_in[9];
  const float* k1w  = (const float*)d_in[10]; const float* k1b = (const float*)d_in[11];
  const float* k2w  = (const float*)d_in[12]; const float* k2b = (const float*)d_in[13];
  const float* v1w  = (const float*)d_in[14]; const float* v1b = (const float*)d_in[15];
  const float* v2w  = (const float*)d_in[16]; const float* v2b = (const float*)d_in[17];
  const float* p1w  = (const float*)d_in[18]; const float* p1b = (const float*)d_in[19];
  const float* p2w  = (const float*)d_in[20]; const float* p2b = (const float*)d_in[21];
  const float* rpbt = (const float*)d_in[22];
  const int*   rpi  = (const int*)d_in[23];
  char* ws = (char*)d_ws;
  float* o = (float*)d_out;

  pre_a<<<49, 384, 0, stream>>>(q1w,q2w,k1w,k2w,v1w,v2w,p1w,p2w, w1,b1,w2, rpbt, ls, ws);
  pre_b<<<384, 256, 0, stream>>>(mask, rpi, ws);
  win_attn<<<2048, 768, 0, stream>>>(x, ws, q1b,q2b,k1b,k2b,v1b,v2b,p1b,p2b, o);
}

// Round 17
// 187.544 us; speedup vs baseline: 1.8782x; 1.0526x over previous
//
#include <hip/hip_runtime.h>
#include <hip/hip_bf16.h>

#define NT 64
#define DM 192
#define LOG2E 1.4426950408889634f

typedef __attribute__((ext_vector_type(4))) float f32x4;
typedef __attribute__((ext_vector_type(4))) float float4v;
using half2v = __attribute__((ext_vector_type(2))) _Float16;
using half4v = __attribute__((ext_vector_type(4))) _Float16;
using half8v = __attribute__((ext_vector_type(8))) _Float16;

// ws layout (bytes)
#define BIAS_OFF  147456      // 8*6*3*1024 W-frags
#define TAB_OFF   6438912     // BIAS_OFF + 384*16*64*16
#define SCALE_OFF 6444312

__device__ __forceinline__ half4v pk4(float a, float b, float c, float d){
  half2v lo = __builtin_bit_cast(half2v, __builtin_amdgcn_cvt_pkrtz(a, b));
  half2v hi = __builtin_bit_cast(half2v, __builtin_amdgcn_cvt_pkrtz(c, d));
  half4v r; r[0]=lo[0]; r[1]=lo[1]; r[2]=hi[0]; r[3]=hi[1];
  return r;
}
// native 2^x (v_exp_f32 is exp2)
__device__ __forceinline__ float exp2v(float x){
  float r;
  asm("v_exp_f32 %0, %1" : "=v"(r) : "v"(x));
  return r;
}

// ---------------- precompute A: W frags in 16x16x32 layout + rpb-mlp table + scales ----------------
__global__ __launch_bounds__(384) void pre_a(
  const float* __restrict__ q1w, const float* __restrict__ q2w,
  const float* __restrict__ k1w, const float* __restrict__ k2w,
  const float* __restrict__ v1w, const float* __restrict__ v2w,
  const float* __restrict__ p1w, const float* __restrict__ p2w,
  const float* __restrict__ w1, const float* __restrict__ b1,
  const float* __restrict__ w2, const float* __restrict__ rpbt,
  const float* __restrict__ ls, char* __restrict__ ws)
{
  int blk = blockIdx.x, t = threadIdx.x;
  if (blk < 48) {
    const float* Ws[8] = {q1w,q2w,k1w,k2w,v1w,v2w,p1w,p2w};
    int mat = blk / 6, ct = blk % 6;
    int lane = t & 63, ks = t >> 6;        // ks 0..5, only 0..2 used
    if (ks < 3) {
      const float* W = Ws[mat];
      int c  = 16*ct + (lane & 15);
      int d0 = 32*ks + 8*(lane >> 4);
      half8v h;
      #pragma unroll
      for (int j = 0; j < 8; ++j) {
        float wel = W[c*96 + d0 + j];
        if (mat < 6 && c == d0 + j) wel += 1.0f;   // fold residual identity
        h[j] = (_Float16)wel;
      }
      *(half8v*)(ws + (size_t)((mat*6+ct)*3+ks)*1024 + lane*16) = h;
    }
  } else {
    float* tab = (float*)(ws + TAB_OFF);
    if (t < 225) {
      float t0 = rpbt[2*t], t1 = rpbt[2*t+1];
      float acc[6] = {0,0,0,0,0,0};
      for (int j = 0; j < 128; ++j) {
        float hv = fmaxf(t0*w1[2*j] + t1*w1[2*j+1] + b1[j], 0.f);
        #pragma unroll
        for (int hh = 0; hh < 6; ++hh) acc[hh] += hv * w2[hh*128 + j];
      }
      #pragma unroll
      for (int hh = 0; hh < 6; ++hh) tab[t*6 + hh] = acc[hh];
    }
    if (t >= 240 && t < 246) {
      float* sc = (float*)(ws + SCALE_OFF);
      int i = t - 240;
      sc[i] = expf(fminf(ls[i], 4.605170185988091f)) * LOG2E; // log(100); exp2-folded
    }
  }
}

// ---------------- precompute B: bias = log2e*(16*sigmoid(rpb)+mask) in S^T fragment order ----------------
__global__ __launch_bounds__(256) void pre_b(
  const float* __restrict__ mask, const int* __restrict__ rpi,
  char* __restrict__ ws)
{
  int w = blockIdx.x / 6, h = blockIdx.x % 6;
  int lane = threadIdx.x & 63, nt = threadIdx.x >> 6;
  const float* tab = (const float*)(ws + TAB_OFF);
  float* bias = (float*)(ws + BIAS_OFF);
  #pragma unroll
  for (int mt = 0; mt < 4; ++mt)
    #pragma unroll
    for (int r = 0; r < 4; ++r) {
      int m = 16*mt + ((lane >> 4) << 2) + r;
      int n = 16*nt + (lane & 15);
      int idx = rpi[n*64 + m];
      float tv = tab[idx*6 + h];
      float sg = 16.f / (1.f + expf(-tv));
      float mv = mask[(w*64 + n)*64 + m];
      bias[(size_t)(((w*6+h)*4+mt)*4+nt)*256 + lane*4 + r] = (sg + mv) * LOG2E;
    }
}

// ---------------- main fused kernel: 1 block = 2 windows, 12 waves = 2 x (6 heads) ----------------
// r16 champion + (1) separate o-buffer: removes the pre-o-store barrier (3->2 barriers/pass),
// (2) S-phase bias loads software-pipelined (nt=0 issued behind QK; nt+1 behind softmax(nt)),
// (3) proj weights/bias preloaded before the final barrier (latency hides under the wait).
__global__ __launch_bounds__(768, 2) void win_attn(
  const float* __restrict__ x, const char* __restrict__ ws,
  const float* __restrict__ q1b, const float* __restrict__ q2b,
  const float* __restrict__ k1b, const float* __restrict__ k2b,
  const float* __restrict__ v1b, const float* __restrict__ v2b,
  const float* __restrict__ p1b, const float* __restrict__ p2b,
  float* __restrict__ out)
{
  __shared__ __align__(16) _Float16 xo2[2][64*200];   // per-window x (f16)
  __shared__ __align__(16) _Float16 ob2[2][64*200];   // per-window o (f16)
  const int tid = threadIdx.x;
  const int wv = tid >> 6, lane = tid & 63;
  const int llo = lane & 15, lhi = lane >> 4;
  const int wgrp = (wv >= 6) ? 1 : 0;   // which window in this block
  const int h = wv - 6*wgrp;            // head 0..5
  // XCD swizzle: group g = b0%32 determines the w_in pair; keep each g on one XCD (B%8).
  const int B = blockIdx.x;
  const int g = (((B >> 3) >> 6) << 3) | (B & 7);
  const int kk = (B >> 3) & 63;
  const int b0 = kk*32 + g;
  const int b = b0*2 + wgrp, w_in = b & 63;
  const int lt = tid - 384*wgrp;        // thread id within window group (0..383)
  _Float16* xo = xo2[wgrp];
  _Float16* ob = ob2[wgrp];
  const int half = (h < 3) ? 0 : 1;
  const int hd0 = 32 * (h % 3);                   // head-dim base within half
  const f32x4 zf = {0.f,0.f,0.f,0.f};
  const float* xg = x + (size_t)b * (NT*DM);

  // ---- stage x -> LDS f16 (coalesced float4 loads, packed cvt, 8B stores) ----
  float4v xv[8];
  #pragma unroll
  for (int it = 0; it < 8; ++it) xv[it] = *(const float4v*)(xg + 4*(lt + it*384));
  #pragma unroll
  for (int it = 0; it < 8; ++it) {
    int f4 = lt + it*384;
    int row = f4 / 48, c4 = f4 % 48;
    *(half4v*)(xo + row*200 + c4*4) = pk4(xv[it][0], xv[it][1], xv[it][2], xv[it][3]);
  }
  __syncthreads();   // (1) x staged

  const float scale_h = ((const float*)(ws + SCALE_OFF))[h];
  const float4v* biasf = (const float4v*)(ws + BIAS_OFF);

  // ---- issue nt=0 bias loads now; they complete behind the QK phase (vmcnt in-order) ----
  f32x4 bb[4];
  #pragma unroll
  for (int mt = 0; mt < 4; ++mt)
    bb[mt] = *(const f32x4*)&biasf[(size_t)(((w_in*6 + h)*4 + mt)*4 + 0)*64 + lane];

  // ---- joint QK pass (x32): acc init = bias fragment; l2norm (tree) -> qf/kf frags ----
  half4v qf[2][4], kf[2][4];
  {
    const float* qbp = half ? q2b : q1b;
    const float* kbp = half ? k2b : k1b;
    f32x4 qacc[2][4], kacc[2][4];
    #pragma unroll
    for (int dt = 0; dt < 2; ++dt) {
      f32x4 qb = *(const f32x4*)(qbp + hd0 + 16*dt + 4*lhi);
      f32x4 kb = *(const f32x4*)(kbp + hd0 + 16*dt + 4*lhi);
      #pragma unroll
      for (int tt = 0; tt < 4; ++tt) { qacc[dt][tt] = qb; kacc[dt][tt] = kb; }
    }
    __builtin_amdgcn_s_setprio(1);
    #pragma unroll
    for (int ks = 0; ks < 3; ++ks) {
      half8v xf[4];
      #pragma unroll
      for (int tt = 0; tt < 4; ++tt)
        xf[tt] = *(const half8v*)(xo + (16*tt+llo)*200 + half*96 + 32*ks + 8*lhi);
      #pragma unroll
      for (int dt = 0; dt < 2; ++dt) {
        half8v wq = *(const half8v*)(ws + (size_t)(((0+half)*6 + 2*(h%3)+dt)*3 + ks)*1024 + lane*16);
        half8v wk = *(const half8v*)(ws + (size_t)(((2+half)*6 + 2*(h%3)+dt)*3 + ks)*1024 + lane*16);
        #pragma unroll
        for (int tt = 0; tt < 4; ++tt) {
          qacc[dt][tt] = __builtin_amdgcn_mfma_f32_16x16x32_f16(wq, xf[tt], qacc[dt][tt], 0,0,0);
          kacc[dt][tt] = __builtin_amdgcn_mfma_f32_16x16x32_f16(wk, xf[tt], kacc[dt][tt], 0,0,0);
        }
      }
    }
    __builtin_amdgcn_s_setprio(0);
    #pragma unroll
    for (int tt = 0; tt < 4; ++tt) {
      f32x4 q0 = qacc[0][tt], q1 = qacc[1][tt];
      f32x4 k0 = kacc[0][tt], k1 = kacc[1][tt];
      float sq = ((q0[0]*q0[0] + q0[1]*q0[1]) + (q0[2]*q0[2] + q0[3]*q0[3]))
               + ((q1[0]*q1[0] + q1[1]*q1[1]) + (q1[2]*q1[2] + q1[3]*q1[3]));
      float sk = ((k0[0]*k0[0] + k0[1]*k0[1]) + (k0[2]*k0[2] + k0[3]*k0[3]))
               + ((k1[0]*k1[0] + k1[1]*k1[1]) + (k1[2]*k1[2] + k1[3]*k1[3]));
      sq += __shfl_xor(sq, 16); sq += __shfl_xor(sq, 32);
      sk += __shfl_xor(sk, 16); sk += __shfl_xor(sk, 32);
      float invq = scale_h * __builtin_amdgcn_rsqf(fmaxf(sq, 1e-24f));  // == scale/max(sqrt,1e-12)
      float invk = __builtin_amdgcn_rsqf(fmaxf(sk, 1e-24f));
      qf[0][tt] = pk4(q0[0]*invq, q0[1]*invq, q0[2]*invq, q0[3]*invq);
      qf[1][tt] = pk4(q1[0]*invq, q1[1]*invq, q1[2]*invq, q1[3]*invq);
      kf[0][tt] = pk4(k0[0]*invk, k0[1]*invk, k0[2]*invk, k0[3]*invk);
      kf[1][tt] = pk4(k1[0]*invk, k1[1]*invk, k1[2]*invk, k1[3]*invk);
    }
  }

  // ---- S^T = kn*qn^T + bias (C operand, pipelined loads), softmax in exp2 domain ----
  half4v pf[4][4];
  float inv_s[4];
  #pragma unroll
  for (int nt = 0; nt < 4; ++nt) {
    f32x4 s[4];
    __builtin_amdgcn_s_setprio(1);
    #pragma unroll
    for (int mt = 0; mt < 4; ++mt) {
      f32x4 t0 = __builtin_amdgcn_mfma_f32_16x16x16f16(kf[0][mt], qf[0][nt], bb[mt], 0,0,0);
      s[mt]    = __builtin_amdgcn_mfma_f32_16x16x16f16(kf[1][mt], qf[1][nt], t0, 0,0,0);
    }
    __builtin_amdgcn_s_setprio(0);
    // issue next nt's bias loads; they land behind this nt's softmax VALU
    f32x4 bbn[4];
    if (nt < 3) {
      #pragma unroll
      for (int mt = 0; mt < 4; ++mt)
        bbn[mt] = *(const f32x4*)&biasf[(size_t)(((w_in*6 + h)*4 + mt)*4 + (nt+1))*64 + lane];
    }
    float m0 = fmaxf(fmaxf(s[0][0], s[0][1]), fmaxf(s[0][2], s[0][3]));
    float m1 = fmaxf(fmaxf(s[1][0], s[1][1]), fmaxf(s[1][2], s[1][3]));
    float m2 = fmaxf(fmaxf(s[2][0], s[2][1]), fmaxf(s[2][2], s[2][3]));
    float m3 = fmaxf(fmaxf(s[3][0], s[3][1]), fmaxf(s[3][2], s[3][3]));
    float mx = fmaxf(fmaxf(m0, m1), fmaxf(m2, m3));
    mx = fmaxf(mx, __shfl_xor(mx, 16)); mx = fmaxf(mx, __shfl_xor(mx, 32));
    float e[4][4];
    #pragma unroll
    for (int mt = 0; mt < 4; ++mt)
      #pragma unroll
      for (int r = 0; r < 4; ++r) e[mt][r] = exp2v(s[mt][r] - mx);
    float t0s = (e[0][0]+e[0][1]) + (e[0][2]+e[0][3]);
    float t1s = (e[1][0]+e[1][1]) + (e[1][2]+e[1][3]);
    float t2s = (e[2][0]+e[2][1]) + (e[2][2]+e[2][3]);
    float t3s = (e[3][0]+e[3][1]) + (e[3][2]+e[3][3]);
    float sum = (t0s+t1s) + (t2s+t3s);
    sum += __shfl_xor(sum, 16); sum += __shfl_xor(sum, 32);
    inv_s[nt] = __builtin_amdgcn_rcpf(sum);   // sum >= 1, approx rcp safe
    #pragma unroll
    for (int mt = 0; mt < 4; ++mt)
      pf[mt][nt] = pk4(e[mt][0], e[mt][1], e[mt][2], e[mt][3]);
    if (nt < 3) {
      #pragma unroll
      for (int mt = 0; mt < 4; ++mt) bb[mt] = bbn[mt];   // renamed away by unroll
    }
  }

  // ---- V pass (x32): acc init = bias splat -> vf frags ----
  half4v vf[4][2];
  {
    const float* vbp = half ? v2b : v1b;
    f32x4 acc[4][2];
    #pragma unroll
    for (int ct = 0; ct < 2; ++ct) {
      float vb = vbp[hd0 + 16*ct + llo];
      f32x4 vbv = {vb, vb, vb, vb};
      #pragma unroll
      for (int tt = 0; tt < 4; ++tt) acc[tt][ct] = vbv;
    }
    __builtin_amdgcn_s_setprio(1);
    #pragma unroll
    for (int ks = 0; ks < 3; ++ks) {
      half8v xf[4];
      #pragma unroll
      for (int tt = 0; tt < 4; ++tt)
        xf[tt] = *(const half8v*)(xo + (16*tt+llo)*200 + half*96 + 32*ks + 8*lhi);
      #pragma unroll
      for (int ct = 0; ct < 2; ++ct) {
        half8v wvf = *(const half8v*)(ws + (size_t)(((4+half)*6 + 2*(h%3)+ct)*3 + ks)*1024 + lane*16);
        #pragma unroll
        for (int tt = 0; tt < 4; ++tt)
          acc[tt][ct] = __builtin_amdgcn_mfma_f32_16x16x32_f16(xf[tt], wvf, acc[tt][ct], 0,0,0);
      }
    }
    __builtin_amdgcn_s_setprio(0);
    #pragma unroll
    for (int ct = 0; ct < 2; ++ct)
      #pragma unroll
      for (int tt = 0; tt < 4; ++tt)
        vf[tt][ct] = pk4(acc[tt][ct][0], acc[tt][ct][1], acc[tt][ct][2], acc[tt][ct][3]);
  }

  // ---- o^T = V^T * P^T (x16, all-register), normalize at store -> ob (no pre-barrier) ----
  f32x4 oacc[2][4];
  #pragma unroll
  for (int dt = 0; dt < 2; ++dt)
    #pragma unroll
    for (int nt = 0; nt < 4; ++nt) oacc[dt][nt] = zf;
  __builtin_amdgcn_s_setprio(1);
  #pragma unroll
  for (int mt = 0; mt < 4; ++mt)
    #pragma unroll
    for (int dt = 0; dt < 2; ++dt)
      #pragma unroll
      for (int nt = 0; nt < 4; ++nt)
        oacc[dt][nt] = __builtin_amdgcn_mfma_f32_16x16x16f16(vf[mt][dt], pf[mt][nt], oacc[dt][nt], 0,0,0);
  __builtin_amdgcn_s_setprio(0);
  #pragma unroll
  for (int dt = 0; dt < 2; ++dt)
    #pragma unroll
    for (int nt = 0; nt < 4; ++nt)
      *(half4v*)(ob + (16*nt+llo)*200 + 32*h + 16*dt + 4*lhi) =
        pk4(oacc[dt][nt][0]*inv_s[nt], oacc[dt][nt][1]*inv_s[nt],
            oacc[dt][nt][2]*inv_s[nt], oacc[dt][nt][3]*inv_s[nt]);

  // ---- preload proj weights/bias; latency hides under the barrier wait ----
  const int ph = h & 1;
  const int cp = h >> 1;          // 0..2
  const float* pbp = ph ? p2b : p1b;
  half8v wpr[3][2];
  #pragma unroll
  for (int ks = 0; ks < 3; ++ks)
    #pragma unroll
    for (int cc = 0; cc < 2; ++cc)
      wpr[ks][cc] = *(const half8v*)(ws + (size_t)(((6+ph)*6 + 2*cp+cc)*3 + ks)*1024 + lane*16);
  f32x4 pb[2];
  #pragma unroll
  for (int cc = 0; cc < 2; ++cc)
    pb[cc] = *(const f32x4*)(pbp + 16*(2*cp+cc) + 4*lhi);

  __syncthreads();   // (2) o complete (all heads of this window)

  // ---- final^T = Wp * o^T (x32); acc init = proj bias ----
  f32x4 facc[2][4];
  #pragma unroll
  for (int cc = 0; cc < 2; ++cc)
    #pragma unroll
    for (int nt = 0; nt < 4; ++nt) facc[cc][nt] = pb[cc];
  #pragma unroll
  for (int ks = 0; ks < 3; ++ks) {
    half8v of[4];
    #pragma unroll
    for (int nt = 0; nt < 4; ++nt)
      of[nt] = *(const half8v*)(ob + (16*nt+llo)*200 + 96*ph + 32*ks + 8*lhi);
    #pragma unroll
    for (int cc = 0; cc < 2; ++cc)
      #pragma unroll
      for (int nt = 0; nt < 4; ++nt)
        facc[cc][nt] = __builtin_amdgcn_mfma_f32_16x16x32_f16(wpr[ks][cc], of[nt], facc[cc][nt], 0,0,0);
  }
  float* og = out + (size_t)b * (NT*DM);
  #pragma unroll
  for (int cc = 0; cc < 2; ++cc)
    #pragma unroll
    for (int nt = 0; nt < 4; ++nt) {
      float4v res = {facc[cc][nt][0], facc[cc][nt][1], facc[cc][nt][2], facc[cc][nt][3]};
      *(float4v*)(og + (size_t)(16*nt+llo)*192 + 96*ph + 16*(2*cp+cc) + 4*lhi) = res;
    }
}

extern "C" void kernel_launch(void* const* d_in, const int* in_sizes, int n_in,
                              void* d_out, int out_size, void* d_ws, size_t ws_size,
                              hipStream_t stream)
{
  const float* x    = (const float*)d_in[0];
  const float* mask = (const float*)d_in[1];
  const float* ls   = (const float*)d_in[2];
  const float* w1   = (const float*)d_in[3];
  const float* b1   = (const float*)d_in[4];
  const float* w2   = (const float*)d_in[5];
  const float* q1w  = (const float*)d_in[6];  const float* q1b = (const float*)d_in[7];
  const float* q2w  = (const float*)d_in[8];  const float* q2b = (const float*)d_in[9];
  const float* k1w  = (const float*)d_in[10]; const float* k1b = (const float*)d_in[11];
  const float* k2w  = (const float*)d_in[12]; const float* k2b = (const float*)d_in[13];
  const float* v1w  = (const float*)d_in[14]; const float* v1b = (const float*)d_in[15];
  const float* v2w  = (const float*)d_in[16]; const float* v2b = (const float*)d_in[17];
  const float* p1w  = (const float*)d_in[18]; const float* p1b = (const float*)d_in[19];
  const float* p2w  = (const float*)d_in[20]; const float* p2b = (const float*)d_in[21];
  const float* rpbt = (const float*)d_in[22];
  const int*   rpi  = (const int*)d_in[23];
  char* ws = (char*)d_ws;
  float* o = (float*)d_out;

  pre_a<<<49, 384, 0, stream>>>(q1w,q2w,k1w,k2w,v1w,v2w,p1w,p2w, w1,b1,w2, rpbt, ls, ws);
  pre_b<<<384, 256, 0, stream>>>(mask, rpi, ws);
  win_attn<<<2048, 768, 0, stream>>>(x, ws, q1b,q2b,k1b,k2b,v1b,v2b,p1b,p2b, o);
}